// Round 2
// baseline (194.990 us; speedup 1.0000x reference)
//
#include <hip/hip_runtime.h>
#include <hip/hip_bf16.h>
#include <math.h>

#define N_TOT 1024
#define C_DIM 4096
#define T_MARGIN 3e-4f   // coarse fp16 cosine err sigma ~6e-6; 3e-4 = ~50 sigma

typedef __attribute__((ext_vector_type(8))) _Float16 half8;
typedef __attribute__((ext_vector_type(8))) unsigned short ushort8;
typedef __attribute__((ext_vector_type(8))) char schar8;
typedef __attribute__((ext_vector_type(4))) float floatx4;

__device__ inline unsigned short f2h(float v) {
    _Float16 h = (_Float16)v;
    return __builtin_bit_cast(unsigned short, h);
}
__device__ inline float h2f(unsigned short u) {
    return (float)__builtin_bit_cast(_Float16, u);
}
// int8 residual with exponent borrowed from the fp16 hi part (err ~ulp/480).
__device__ inline char lo_enc(float v, unsigned short h) {
    int e = (h >> 10) & 31;
    float lo = v - h2f(h);
    float q = rintf(lo * 240.0f * __uint_as_float((unsigned)(152 - e) << 23));
    q = fmaxf(-127.0f, fminf(127.0f, q));
    return (char)(int)q;
}
__device__ inline float lo_dec(char q, unsigned short h) {
    int e = (h >> 10) & 31;
    return (float)q * __uint_as_float((unsigned)(e + 102) << 23) * (1.0f / 240.0f);
}

// lexicographic (value desc, index asc) insert into a sorted top-2 pair
__device__ inline void ins2(float v, int s, float& v1, int& s1, float& v2, int& s2) {
    if (v > v1 || (v == v1 && s < s1)) { v2 = v1; s2 = s1; v1 = v; s1 = s; }
    else if (v > v2 || (v == v2 && s < s2)) { v2 = v; s2 = s; }
}

// ---------------------------------------------------------------------------
// split+transpose+norms: X (C,N) fp32 -> Xhi[n][c] fp16, Xlo[n][c] int8;
// normX[n] += sum_c x^2 (atomic, pre-zeroed). Block (0,0,0) additionally
// computes the flag compaction (colidx, n0). grid (64, 16, 2).
__global__ __launch_bounds__(256) void split_norms(const float* __restrict__ G,
                                                   const float* __restrict__ Kn,
                                                   const float* __restrict__ flag,
                                                   unsigned short* __restrict__ Phi,
                                                   char* __restrict__ Plo,
                                                   unsigned short* __restrict__ Khi,
                                                   char* __restrict__ Klo,
                                                   float* __restrict__ normP,
                                                   float* __restrict__ normK,
                                                   int* __restrict__ colidx,
                                                   int* __restrict__ n0p) {
    const int z = blockIdx.z;
    const float* X = z ? Kn : G;
    unsigned short* Xhi = z ? Khi : Phi;
    char* Xlo = z ? Klo : Plo;
    float* normX = z ? normK : normP;

    __shared__ float tile[64 * 65];
    __shared__ float np[256];
    const int t  = threadIdx.x;
    const int c0 = blockIdx.x * 64;
    const int n0 = blockIdx.y * 64;

    float s2 = 0.0f;
    #pragma unroll
    for (int s = 0; s < 16; s++) {
        int c_loc = s * 4 + (t >> 6);
        int n_loc = t & 63;
        float v = X[(c0 + c_loc) * N_TOT + n0 + n_loc];
        tile[c_loc * 65 + n_loc] = v;
        s2 = fmaf(v, v, s2);
    }
    np[t] = s2;
    __syncthreads();

    if (t < 64) {
        float tot = np[t] + np[t + 64] + np[t + 128] + np[t + 192];
        atomicAdd(&normX[n0 + t], tot);
    }

    #pragma unroll
    for (int s = 0; s < 4; s++) {
        int n_loc = s * 16 + (t >> 4);
        int c4    = (t & 15) * 4;
        unsigned short h[4]; char l[4];
        #pragma unroll
        for (int e = 0; e < 4; e++) {
            float v = tile[(c4 + e) * 65 + n_loc];
            h[e] = f2h(v);
            l[e] = lo_enc(v, h[e]);
        }
        size_t base = (size_t)(n0 + n_loc) * C_DIM + c0 + c4;
        *(ushort4*)&Xhi[base] = make_ushort4(h[0], h[1], h[2], h[3]);
        *(char4*)&Xlo[base]   = make_char4(l[0], l[1], l[2], l[3]);
    }

    // ---- embedded flag scan (block (0,0,0) only; block-uniform branch) ----
    if (blockIdx.x == 0 && blockIdx.y == 0 && blockIdx.z == 0) {
        __shared__ int cz[256];
        __shared__ int co[256];
        float4 fv = *(const float4*)&flag[4 * t];
        int f[4] = {fv.x == 0.0f, fv.y == 0.0f, fv.z == 0.0f, fv.w == 0.0f};
        int nz = f[0] + f[1] + f[2] + f[3];
        cz[t] = nz; co[t] = 4 - nz;
        __syncthreads();
        for (int off = 1; off < 256; off <<= 1) {
            int vz = (t >= off) ? cz[t - off] : 0;
            int vo = (t >= off) ? co[t - off] : 0;
            __syncthreads();
            cz[t] += vz; co[t] += vo;
            __syncthreads();
        }
        const int fn0 = cz[255];
        int zs = cz[t] - nz;
        int os = fn0 + co[t] - (4 - nz);
        #pragma unroll
        for (int e = 0; e < 4; e++) {
            int j = 4 * t + e;
            if (f[e]) colidx[zs++] = j;
            else      colidx[os++] = j;
        }
        if (t == 0) *n0p = fn0;
    }
}

// ---------------------------------------------------------------------------
// coarse fp16 MFMA GEMM vs virtually-compacted B (slot s -> row colidx[s] of
// (s<n0 ? K : P)). 64x128 tile, BK=64, K-split 8 -> grid (16,8,8) = 1024
// blocks, 24 KB LDS, 4 blocks/CU. PLAIN STORES to per-z partial planes
// (each element written once -> no atomics, no zeroing).
__global__ __launch_bounds__(256, 4) void gemm_coarse(const unsigned short* __restrict__ Phi,
                                                      const unsigned short* __restrict__ Khi,
                                                      const int* __restrict__ colidx,
                                                      const int* __restrict__ n0p,
                                                      float* __restrict__ dotPart) {
    __shared__ unsigned short sA[64 * 64];    // 8 KB
    __shared__ unsigned short sB[128 * 64];   // 16 KB

    const int t    = threadIdx.x;
    const int wave = t >> 6, lane = t & 63;
    const int wm   = wave >> 1, wn = wave & 1;
    const int quad = lane >> 4, lrow = lane & 15;
    const int ib = blockIdx.x * 64, jb = blockIdx.y * 128;
    const int bz = blockIdx.z;
    const int k_beg = bz * 512;
    const int n0 = *n0p;

    const int srow = t >> 3;            // 0..31
    const int g    = (t & 7) ^ (srow & 7);

    const unsigned short* gA[2];
    gA[0] = Phi + (size_t)(ib + srow) * C_DIM + g * 8;
    gA[1] = gA[0] + (size_t)32 * C_DIM;
    const unsigned short* gB[4];
    #pragma unroll
    for (int q = 0; q < 4; q++) {
        int s = jb + q * 32 + srow;
        int row = colidx[s];
        const unsigned short* src = (s < n0) ? Khi : Phi;
        gB[q] = src + (size_t)row * C_DIM + g * 8;
    }

    floatx4 acc[2][4] = {};

    for (int k0 = k_beg; k0 < k_beg + 512; k0 += 64) {
        #pragma unroll
        for (int q = 0; q < 2; q++)
            __builtin_amdgcn_global_load_lds(
                (const __attribute__((address_space(1))) void*)(gA[q] + k0),
                (__attribute__((address_space(3))) void*)((char*)sA + q * 4096 + t * 16), 16, 0, 0);
        #pragma unroll
        for (int q = 0; q < 4; q++)
            __builtin_amdgcn_global_load_lds(
                (const __attribute__((address_space(1))) void*)(gB[q] + k0),
                (__attribute__((address_space(3))) void*)((char*)sB + q * 4096 + t * 16), 16, 0, 0);
        __syncthreads();

        #pragma unroll
        for (int kk = 0; kk < 2; kk++) {
            const int gk = kk * 4 + quad;
            half8 a[2], b[4];
            #pragma unroll
            for (int ti = 0; ti < 2; ti++) {
                int m = wm * 32 + ti * 16 + lrow;
                a[ti] = *(const half8*)&sA[m * 64 + ((gk ^ (m & 7)) << 3)];
            }
            #pragma unroll
            for (int tj = 0; tj < 4; tj++) {
                int n = wn * 64 + tj * 16 + lrow;
                b[tj] = *(const half8*)&sB[n * 64 + ((gk ^ (n & 7)) << 3)];
            }
            #pragma unroll
            for (int ti = 0; ti < 2; ti++)
                #pragma unroll
                for (int tj = 0; tj < 4; tj++)
                    acc[ti][tj] = __builtin_amdgcn_mfma_f32_16x16x32_f16(a[ti], b[tj], acc[ti][tj], 0, 0, 0);
        }
        __syncthreads();
    }

    // plain stores into this z's private plane. C/D: col=lane&15, row=quad*4+reg
    float* outp = dotPart + ((size_t)bz << 20);
    #pragma unroll
    for (int tj = 0; tj < 4; tj++) {
        int j = jb + wn * 64 + tj * 16 + lrow;
        #pragma unroll
        for (int ti = 0; ti < 2; ti++) {
            #pragma unroll
            for (int reg = 0; reg < 4; reg++) {
                int i = ib + wm * 32 + ti * 16 + quad * 4 + reg;
                outp[i * N_TOT + j] = acc[ti][tj][reg];
            }
        }
    }
}

// ---------------------------------------------------------------------------
// pass1: one block per row. Sum 8 partial planes, coarse cosines, single-pass
// top-2 per partition, threshold candidate ballot. Trusted (row,zz): write
// w01/i01 + meanAcc atomics. Untrusted: append work item to worklist.
// NO refine here -> blocks retire at memory-phase speed; tiny LDS.
__global__ __launch_bounds__(256) void topk_pass1(const float* __restrict__ dotPart,
                                                  const float* __restrict__ flag,
                                                  const float* __restrict__ normP,
                                                  const float* __restrict__ normK,
                                                  const int* __restrict__ colidx,
                                                  const int* __restrict__ n0p,
                                                  float* __restrict__ w01,   // [2][N][2]
                                                  int* __restrict__ i01,     // [2][N][2]
                                                  float* __restrict__ meanAcc,  // [4], zeroed
                                                  int* __restrict__ wlCount,    // zeroed
                                                  int* __restrict__ wl_hdr,     // [2048]
                                                  int* __restrict__ wl_cand) {  // [2048][16]
    __shared__ float sr_v1[2][4], sr_v2[2][4];
    __shared__ int   sr_s1[2][4], sr_s2[2][4];
    __shared__ int   s_cnt[2];
    __shared__ int   s_cand[2][16];
    __shared__ int   s_slot[2];

    const int row = blockIdx.x;
    const int t   = threadIdx.x;
    const int wave = t >> 6, lane = t & 63;
    const int n0 = *n0p;
    const float nr = normP[row];

    if (t < 2) s_cnt[t] = 0;

    // sum the 8 K-split partials for my 4 slots
    float4 dv = make_float4(0.f, 0.f, 0.f, 0.f);
    #pragma unroll
    for (int z = 0; z < 8; z++) {
        float4 p = *(const float4*)&dotPart[((size_t)z << 20) + (size_t)row * N_TOT + 4 * t];
        dv.x += p.x; dv.y += p.y; dv.z += p.z; dv.w += p.w;
    }

    // coarse cosines for my 4 compacted slots
    float cv[4];
    #pragma unroll
    for (int e = 0; e < 4; e++) {
        int s = 4 * t + e;
        int gj = colidx[s];
        float nb = (s < n0) ? normK[gj] : normP[gj];
        float d  = (e == 0) ? dv.x : (e == 1) ? dv.y : (e == 2) ? dv.z : dv.w;
        cv[e] = d * rsqrtf(nr * nb);
    }

    // single-pass wave-local top-2 per partition (no barriers inside)
    #pragma unroll
    for (int zz = 0; zz < 2; zz++) {
        float v1 = -INFINITY, v2 = -INFINITY;
        int   s1 = 0x7FFFFFFF, s2 = 0x7FFFFFFF;
        #pragma unroll
        for (int e = 0; e < 4; e++) {
            int s = 4 * t + e;
            bool inz = zz ? (s >= n0) : (s < n0);
            if (inz) ins2(cv[e], s, v1, s1, v2, s2);
        }
        #pragma unroll
        for (int off = 32; off > 0; off >>= 1) {
            float o1 = __shfl_xor(v1, off); int q1 = __shfl_xor(s1, off);
            float o2 = __shfl_xor(v2, off); int q2 = __shfl_xor(s2, off);
            ins2(o1, q1, v1, s1, v2, s2);
            ins2(o2, q2, v1, s1, v2, s2);
        }
        if (lane == 0) {
            sr_v1[zz][wave] = v1; sr_s1[zz][wave] = s1;
            sr_v2[zz][wave] = v2; sr_s2[zz][wave] = s2;
        }
    }
    __syncthreads();

    // cross-wave merge (uniform in all threads) + threshold candidate ballot
    float m1z[2], m2z[2]; int b1z[2], b2z[2];
    #pragma unroll
    for (int zz = 0; zz < 2; zz++) {
        float m1 = -INFINITY, m2 = -INFINITY;
        int   b1 = 0x7FFFFFFF, b2 = 0x7FFFFFFF;
        #pragma unroll
        for (int w = 0; w < 4; w++) {
            ins2(sr_v1[zz][w], sr_s1[zz][w], m1, b1, m2, b2);
            ins2(sr_v2[zz][w], sr_s2[zz][w], m1, b1, m2, b2);
        }
        m1z[zz] = m1; m2z[zz] = m2; b1z[zz] = b1; b2z[zz] = b2;
        const float thr = m2 - T_MARGIN;
        #pragma unroll
        for (int e = 0; e < 4; e++) {
            int s = 4 * t + e;
            bool inz = zz ? (s >= n0) : (s < n0);
            if (inz && cv[e] > thr) {
                int idx = atomicAdd(&s_cnt[zz], 1);
                if (idx < 16) s_cand[zz][idx] = s;  // >16 cands: graceful cap
            }
        }
    }
    __syncthreads();

    const bool fr = (flag[row] == 1.0f);
    bool need[2]; int cntz[2];
    #pragma unroll
    for (int zz = 0; zz < 2; zz++) {
        const int cnt = min(s_cnt[zz], 16);
        cntz[zz] = cnt;
        const bool trusted = (s_cnt[zz] == 2) && (m1z[zz] - m2z[zz] > T_MARGIN);
        need[zz] = !trusted;
        if (t == 0) {
            if (trusted) {
                int base = (zz * N_TOT + row) * 2;
                w01[base]     = m1z[zz];
                w01[base + 1] = m2z[zz];
                i01[base]     = colidx[b1z[zz]];
                i01[base + 1] = colidx[b2z[zz]];
                if (fr) {
                    atomicAdd(&meanAcc[zz * 2],     m1z[zz]);
                    atomicAdd(&meanAcc[zz * 2 + 1], m2z[zz]);
                }
            } else {
                int slot = atomicAdd(wlCount, 1);
                s_slot[zz] = slot;
                wl_hdr[slot] = row | (zz << 16) | (cnt << 20);
            }
        }
    }
    __syncthreads();

    #pragma unroll
    for (int zz = 0; zz < 2; zz++)
        if (need[zz] && t < cntz[zz])
            wl_cand[s_slot[zz] * 16 + t] = s_cand[zz][t];
}

// ---------------------------------------------------------------------------
// refine2: grid-stride over the worklist; ONE BLOCK PER (row,zz) work item.
// Reconstruct the exact A row in LDS, 8 parallel 32-lane candidate dots
// (two passes if cnt>8), exact top-2 with global-index tie-break.
__global__ __launch_bounds__(256) void refine2(const unsigned short* __restrict__ Phi,
                                               const char* __restrict__ Plo,
                                               const unsigned short* __restrict__ Khi,
                                               const char* __restrict__ Klo,
                                               const float* __restrict__ normP,
                                               const float* __restrict__ normK,
                                               const int* __restrict__ colidx,
                                               const int* __restrict__ n0p,
                                               const float* __restrict__ flag,
                                               const int* __restrict__ wlCount,
                                               const int* __restrict__ wl_hdr,
                                               const int* __restrict__ wl_cand,
                                               float* __restrict__ w01,
                                               int* __restrict__ i01,
                                               float* __restrict__ meanAcc) {
    __shared__ float sAf[C_DIM];     // 16 KB exact A row
    __shared__ float s_rcv[16];
    __shared__ int   s_rcj[16];

    const int t   = threadIdx.x;
    const int grp = t >> 5, l32 = t & 31;
    const int total = *wlCount;
    const int n0 = *n0p;

    for (int item = blockIdx.x; item < total; item += gridDim.x) {
        const int hdr = wl_hdr[item];
        const int row = hdr & 0xFFFF;
        const int zz  = (hdr >> 16) & 1;
        const int cnt = hdr >> 20;
        const float nr = normP[row];

        // reconstruct exact A row
        {
            const unsigned short* Ah = Phi + (size_t)row * C_DIM;
            const char*           Al = Plo + (size_t)row * C_DIM;
            #pragma unroll
            for (int s = 0; s < 2; s++) {
                int c = t * 16 + s * 8;
                ushort8 hb = *(const ushort8*)&Ah[c];
                schar8  lb = *(const schar8*)&Al[c];
                #pragma unroll
                for (int e = 0; e < 8; e++) sAf[c + e] = h2f(hb[e]) + lo_dec(lb[e], hb[e]);
            }
        }
        __syncthreads();

        #pragma unroll
        for (int p = 0; p < 2; p++) {
            if (p == 1 && cnt <= 8) break;          // uniform
            const int q = grp + 8 * p;
            float acc = 0.0f;
            int gj = 0; float nb = 1.0f;
            if (q < cnt) {
                const int cs = wl_cand[item * 16 + q];
                gj = colidx[cs];
                nb = (cs < n0) ? normK[gj] : normP[gj];
                const unsigned short* bh_row = ((cs < n0) ? Khi : Phi) + (size_t)gj * C_DIM;
                const char*           bl_row = ((cs < n0) ? Klo : Plo) + (size_t)gj * C_DIM;
                #pragma unroll 4
                for (int it = 0; it < 16; it++) {
                    int c = it * 256 + l32 * 8;
                    ushort8 hb = *(const ushort8*)&bh_row[c];
                    schar8  lb = *(const schar8*)&bl_row[c];
                    #pragma unroll
                    for (int e = 0; e < 8; e++)
                        acc = fmaf(sAf[c + e], h2f(hb[e]) + lo_dec(lb[e], hb[e]), acc);
                }
            }
            #pragma unroll
            for (int off = 16; off > 0; off >>= 1) acc += __shfl_xor(acc, off);
            if (l32 == 0 && q < cnt) {
                s_rcv[q] = acc * rsqrtf(nr * nb);
                s_rcj[q] = gj;
            }
        }
        __syncthreads();

        if (t == 0) {
            float v1 = -INFINITY, v2 = -INFINITY;
            int   j1 = 0x7FFFFFFF, j2 = 0x7FFFFFFF;
            for (int q = 0; q < cnt; q++) {
                float cvx = s_rcv[q];
                int   j   = s_rcj[q];
                if (cvx > v1 || (cvx == v1 && j < j1)) {
                    v2 = v1; j2 = j1; v1 = cvx; j1 = j;
                } else if (cvx > v2 || (cvx == v2 && j < j2)) {
                    v2 = cvx; j2 = j;
                }
            }
            if (j1 == 0x7FFFFFFF) j1 = 0;   // degenerate-partition guard
            if (j2 == 0x7FFFFFFF) j2 = j1;
            int base = (zz * N_TOT + row) * 2;
            w01[base]     = v1;
            w01[base + 1] = v2;
            i01[base]     = j1;
            i01[base + 1] = j2;
            if (flag[row] == 1.0f) {
                atomicAdd(&meanAcc[zz * 2],     v1);
                atomicAdd(&meanAcc[zz * 2 + 1], v2);
            }
        }
        __syncthreads();   // protect sAf/s_rcv before next item
    }
}

// ---------------------------------------------------------------------------
// output: softmax of precomputed meanAcc (no per-block reduction), copy
// generated & known (float4), rtn = weighted gather. grid (4096), block 256.
__global__ __launch_bounds__(256) void output_kernel(const float* __restrict__ G,
                                                     const float* __restrict__ Kn,
                                                     const float* __restrict__ flag,
                                                     const float* __restrict__ w01,
                                                     const int* __restrict__ i01,
                                                     const float* __restrict__ meanAcc,
                                                     const int* __restrict__ n0p,
                                                     float* __restrict__ out) {
    __shared__ float wts[4];
    const int c  = blockIdx.x;
    const int t  = threadIdx.x;
    const int n4 = t * 4;

    if (t == 0) {
        float inv = 1.0f / (float)(N_TOT - *n0p);   // nm = #ones
        float mv[4] = {meanAcc[0] * inv, meanAcc[1] * inv,
                       meanAcc[2] * inv, meanAcc[3] * inv};
        float mx = fmaxf(fmaxf(mv[0], mv[1]), fmaxf(mv[2], mv[3]));
        float e[4], s = 0.0f;
        #pragma unroll
        for (int q = 0; q < 4; q++) { e[q] = expf(mv[q] - mx); s += e[q]; }
        #pragma unroll
        for (int q = 0; q < 4; q++) wts[q] = e[q] / s;
    }
    __syncthreads();
    const float w0 = wts[0], w1 = wts[1], w2 = wts[2], w3 = wts[3];

    float4 fv = *(const float4*)&flag[n4];
    const float fa[4] = {fv.x, fv.y, fv.z, fv.w};

    float4 gv = *(const float4*)&G[c * N_TOT + n4];
    float4 kv = *(const float4*)&Kn[c * N_TOT + n4];
    *(float4*)&out[c * N_TOT + n4] = gv;
    *(float4*)&out[C_DIM * N_TOT + c * N_TOT + n4] = kv;

    float val[4];
    #pragma unroll
    for (int e = 0; e < 4; e++) {
        int n = n4 + e;
        float v = 0.0f;
        if (fa[e] == 1.0f) {
            int c00 = i01[n * 2 + 0];
            int c01 = i01[n * 2 + 1];
            int c10 = i01[2 * N_TOT + n * 2 + 0];
            int c11 = i01[2 * N_TOT + n * 2 + 1];
            v = w0 * Kn[c * N_TOT + c00] + w1 * Kn[c * N_TOT + c01]
              + w2 * G[c * N_TOT + c10]  + w3 * G[c * N_TOT + c11];
        }
        if (n == 0) {
            bool m0 = (flag[0] == 1.0f);
            int c00 = i01[0], c01 = i01[1];
            int c10 = i01[2 * N_TOT], c11 = i01[2 * N_TOT + 1];
            float kn0 = Kn[c * N_TOT];
            float g0  = G[c * N_TOT];
            if (!(m0 && c00 == 0)) v += w0 * kn0;
            if (!(m0 && c01 == 0)) v += w1 * kn0;
            if (!(m0 && c10 == 0)) v += w2 * g0;
            if (!(m0 && c11 == 0)) v += w3 * g0;
        }
        val[e] = v;
    }
    *(float4*)&out[2 * C_DIM * N_TOT + c * N_TOT + n4] =
        make_float4(val[0], val[1], val[2], val[3]);
}

// ---------------------------------------------------------------------------
extern "C" void kernel_launch(void* const* d_in, const int* in_sizes, int n_in,
                              void* d_out, int out_size, void* d_ws, size_t ws_size,
                              hipStream_t stream) {
    const float* G    = (const float*)d_in[0];
    const float* Kn   = (const float*)d_in[1];
    const float* flag = (const float*)d_in[2];
    float* out = (float*)d_out;

    // ws layout (~57 MB; the harness poisons the whole fixed ws allocation
    // regardless, so ws growth is free)
    char* p = (char*)d_ws;
    unsigned short* Phi = (unsigned short*)p;  p += (size_t)N_TOT * C_DIM * 2;  // 8 MB
    unsigned short* Khi = (unsigned short*)p;  p += (size_t)N_TOT * C_DIM * 2;  // 8 MB
    char* Plo = p;                             p += (size_t)N_TOT * C_DIM;      // 4 MB
    char* Klo = p;                             p += (size_t)N_TOT * C_DIM;      // 4 MB
    float* dotPart = (float*)p;                p += (size_t)8 * N_TOT * N_TOT * 4; // 32 MB
    float* normP   = (float*)p;                p += N_TOT * 4;
    float* normK   = (float*)p;                p += N_TOT * 4;
    float* meanAcc = (float*)p;                p += 4 * 4;
    int*   wlCount = (int*)p;                  p += 16;          // pad to 16B
    float* w01     = (float*)p;                p += 4 * N_TOT * 4;
    int*   i01     = (int*)p;                  p += 4 * N_TOT * 4;
    int*   colidx  = (int*)p;                  p += N_TOT * 4;
    int*   n0p     = (int*)p;                  p += 16;
    int*   wl_hdr  = (int*)p;                  p += 2048 * 4;
    int*   wl_cand = (int*)p;

    // zero the atomically-accumulated norms + meanAcc + worklist counter
    hipMemsetAsync(normP, 0, 2 * N_TOT * sizeof(float) + 32, stream);

    split_norms<<<dim3(64, 16, 2), 256, 0, stream>>>(G, Kn, flag, Phi, Plo, Khi, Klo,
                                                     normP, normK, colidx, n0p);
    gemm_coarse<<<dim3(16, 8, 8), 256, 0, stream>>>(Phi, Khi, colidx, n0p, dotPart);
    topk_pass1<<<1024, 256, 0, stream>>>(dotPart, flag, normP, normK, colidx, n0p,
                                         w01, i01, meanAcc, wlCount, wl_hdr, wl_cand);
    refine2<<<1024, 256, 0, stream>>>(Phi, Plo, Khi, Klo, normP, normK, colidx, n0p,
                                      flag, wlCount, wl_hdr, wl_cand, w01, i01, meanAcc);
    output_kernel<<<4096, 256, 0, stream>>>(G, Kn, flag, w01, i01, meanAcc, n0p, out);
}

// Round 4
// 179.903 us; speedup vs baseline: 1.0839x; 1.0839x over previous
//
#include <hip/hip_runtime.h>
#include <hip/hip_bf16.h>
#include <math.h>

#define N_TOT 1024
#define C_DIM 4096
#define T_MARGIN 3e-4f   // coarse fp16 cosine err sigma ~6e-6; 3e-4 = ~50 sigma

typedef __attribute__((ext_vector_type(8))) _Float16 half8;
typedef __attribute__((ext_vector_type(8))) unsigned short ushort8;
typedef __attribute__((ext_vector_type(8))) char schar8;
typedef __attribute__((ext_vector_type(4))) float floatx4;

__device__ inline unsigned short f2h(float v) {
    _Float16 h = (_Float16)v;
    return __builtin_bit_cast(unsigned short, h);
}
__device__ inline float h2f(unsigned short u) {
    return (float)__builtin_bit_cast(_Float16, u);
}
// int8 residual with exponent borrowed from the fp16 hi part (err ~ulp/480).
__device__ inline char lo_enc(float v, unsigned short h) {
    int e = (h >> 10) & 31;
    float lo = v - h2f(h);
    float q = rintf(lo * 240.0f * __uint_as_float((unsigned)(152 - e) << 23));
    q = fmaxf(-127.0f, fminf(127.0f, q));
    return (char)(int)q;
}
__device__ inline float lo_dec(char q, unsigned short h) {
    int e = (h >> 10) & 31;
    return (float)q * __uint_as_float((unsigned)(e + 102) << 23) * (1.0f / 240.0f);
}

// lexicographic (value desc, index asc) insert into a sorted top-2 pair
__device__ inline void ins2(float v, int s, float& v1, int& s1, float& v2, int& s2) {
    if (v > v1 || (v == v1 && s < s1)) { v2 = v1; s2 = s1; v1 = v; s1 = s; }
    else if (v > v2 || (v == v2 && s < s2)) { v2 = v; s2 = s; }
}

// ---------------------------------------------------------------------------
// split+transpose+norms: X (C,N) fp32 -> Xhi[n][c] fp16, Xlo[n][c] int8;
// normX[n] += sum_c x^2 (atomic, pre-zeroed). Block (0,0,0) additionally
// computes the flag compaction (colidx, n0). grid (64, 16, 2).
__global__ __launch_bounds__(256) void split_norms(const float* __restrict__ G,
                                                   const float* __restrict__ Kn,
                                                   const float* __restrict__ flag,
                                                   unsigned short* __restrict__ Phi,
                                                   char* __restrict__ Plo,
                                                   unsigned short* __restrict__ Khi,
                                                   char* __restrict__ Klo,
                                                   float* __restrict__ normP,
                                                   float* __restrict__ normK,
                                                   int* __restrict__ colidx,
                                                   int* __restrict__ n0p) {
    const int z = blockIdx.z;
    const float* X = z ? Kn : G;
    unsigned short* Xhi = z ? Khi : Phi;
    char* Xlo = z ? Klo : Plo;
    float* normX = z ? normK : normP;

    __shared__ float tile[64 * 65];
    __shared__ float np[256];
    const int t  = threadIdx.x;
    const int c0 = blockIdx.x * 64;
    const int n0 = blockIdx.y * 64;

    float s2 = 0.0f;
    #pragma unroll
    for (int s = 0; s < 16; s++) {
        int c_loc = s * 4 + (t >> 6);
        int n_loc = t & 63;
        float v = X[(c0 + c_loc) * N_TOT + n0 + n_loc];
        tile[c_loc * 65 + n_loc] = v;
        s2 = fmaf(v, v, s2);
    }
    np[t] = s2;
    __syncthreads();

    if (t < 64) {
        float tot = np[t] + np[t + 64] + np[t + 128] + np[t + 192];
        atomicAdd(&normX[n0 + t], tot);
    }

    #pragma unroll
    for (int s = 0; s < 4; s++) {
        int n_loc = s * 16 + (t >> 4);
        int c4    = (t & 15) * 4;
        unsigned short h[4]; char l[4];
        #pragma unroll
        for (int e = 0; e < 4; e++) {
            float v = tile[(c4 + e) * 65 + n_loc];
            h[e] = f2h(v);
            l[e] = lo_enc(v, h[e]);
        }
        size_t base = (size_t)(n0 + n_loc) * C_DIM + c0 + c4;
        *(ushort4*)&Xhi[base] = make_ushort4(h[0], h[1], h[2], h[3]);
        *(char4*)&Xlo[base]   = make_char4(l[0], l[1], l[2], l[3]);
    }

    // ---- embedded flag scan (block (0,0,0) only; block-uniform branch) ----
    if (blockIdx.x == 0 && blockIdx.y == 0 && blockIdx.z == 0) {
        __shared__ int cz[256];
        __shared__ int co[256];
        float4 fv = *(const float4*)&flag[4 * t];
        int f[4] = {fv.x == 0.0f, fv.y == 0.0f, fv.z == 0.0f, fv.w == 0.0f};
        int nz = f[0] + f[1] + f[2] + f[3];
        cz[t] = nz; co[t] = 4 - nz;
        __syncthreads();
        for (int off = 1; off < 256; off <<= 1) {
            int vz = (t >= off) ? cz[t - off] : 0;
            int vo = (t >= off) ? co[t - off] : 0;
            __syncthreads();
            cz[t] += vz; co[t] += vo;
            __syncthreads();
        }
        const int fn0 = cz[255];
        int zs = cz[t] - nz;
        int os = fn0 + co[t] - (4 - nz);
        #pragma unroll
        for (int e = 0; e < 4; e++) {
            int j = 4 * t + e;
            if (f[e]) colidx[zs++] = j;
            else      colidx[os++] = j;
        }
        if (t == 0) *n0p = fn0;
    }
}

// ---------------------------------------------------------------------------
// coarse fp16 MFMA GEMM vs virtually-compacted B (slot s -> row colidx[s] of
// (s<n0 ? K : P)). 64x128 tile, BK=64, K-split 8 -> grid (16,8,8) = 1024
// blocks, 24 KB LDS, 4 blocks/CU. PLAIN STORES to per-z partial planes
// (each element written once -> no atomics, no zeroing).
__global__ __launch_bounds__(256, 4) void gemm_coarse(const unsigned short* __restrict__ Phi,
                                                      const unsigned short* __restrict__ Khi,
                                                      const int* __restrict__ colidx,
                                                      const int* __restrict__ n0p,
                                                      float* __restrict__ dotPart) {
    __shared__ unsigned short sA[64 * 64];    // 8 KB
    __shared__ unsigned short sB[128 * 64];   // 16 KB

    const int t    = threadIdx.x;
    const int wave = t >> 6, lane = t & 63;
    const int wm   = wave >> 1, wn = wave & 1;
    const int quad = lane >> 4, lrow = lane & 15;
    const int ib = blockIdx.x * 64, jb = blockIdx.y * 128;
    const int bz = blockIdx.z;
    const int k_beg = bz * 512;
    const int n0 = *n0p;

    const int srow = t >> 3;            // 0..31
    const int g    = (t & 7) ^ (srow & 7);

    const unsigned short* gA[2];
    gA[0] = Phi + (size_t)(ib + srow) * C_DIM + g * 8;
    gA[1] = gA[0] + (size_t)32 * C_DIM;
    const unsigned short* gB[4];
    #pragma unroll
    for (int q = 0; q < 4; q++) {
        int s = jb + q * 32 + srow;
        int row = colidx[s];
        const unsigned short* src = (s < n0) ? Khi : Phi;
        gB[q] = src + (size_t)row * C_DIM + g * 8;
    }

    floatx4 acc[2][4] = {};

    for (int k0 = k_beg; k0 < k_beg + 512; k0 += 64) {
        #pragma unroll
        for (int q = 0; q < 2; q++)
            __builtin_amdgcn_global_load_lds(
                (const __attribute__((address_space(1))) void*)(gA[q] + k0),
                (__attribute__((address_space(3))) void*)((char*)sA + q * 4096 + t * 16), 16, 0, 0);
        #pragma unroll
        for (int q = 0; q < 4; q++)
            __builtin_amdgcn_global_load_lds(
                (const __attribute__((address_space(1))) void*)(gB[q] + k0),
                (__attribute__((address_space(3))) void*)((char*)sB + q * 4096 + t * 16), 16, 0, 0);
        __syncthreads();

        #pragma unroll
        for (int kk = 0; kk < 2; kk++) {
            const int gk = kk * 4 + quad;
            half8 a[2], b[4];
            #pragma unroll
            for (int ti = 0; ti < 2; ti++) {
                int m = wm * 32 + ti * 16 + lrow;
                a[ti] = *(const half8*)&sA[m * 64 + ((gk ^ (m & 7)) << 3)];
            }
            #pragma unroll
            for (int tj = 0; tj < 4; tj++) {
                int n = wn * 64 + tj * 16 + lrow;
                b[tj] = *(const half8*)&sB[n * 64 + ((gk ^ (n & 7)) << 3)];
            }
            #pragma unroll
            for (int ti = 0; ti < 2; ti++)
                #pragma unroll
                for (int tj = 0; tj < 4; tj++)
                    acc[ti][tj] = __builtin_amdgcn_mfma_f32_16x16x32_f16(a[ti], b[tj], acc[ti][tj], 0, 0, 0);
        }
        __syncthreads();
    }

    // plain stores into this z's private plane. C/D: col=lane&15, row=quad*4+reg
    float* outp = dotPart + ((size_t)bz << 20);
    #pragma unroll
    for (int tj = 0; tj < 4; tj++) {
        int j = jb + wn * 64 + tj * 16 + lrow;
        #pragma unroll
        for (int ti = 0; ti < 2; ti++) {
            #pragma unroll
            for (int reg = 0; reg < 4; reg++) {
                int i = ib + wm * 32 + ti * 16 + quad * 4 + reg;
                outp[i * N_TOT + j] = acc[ti][tj][reg];
            }
        }
    }
}

// ---------------------------------------------------------------------------
// sum8: streaming reduction of the 8 K-split planes IN PLACE into plane 0.
// grid 1024 x 256: exactly one float4 per thread over the 2^20-elem plane.
// Each element read/written by exactly one thread -> no races.
__global__ __launch_bounds__(256) void sum8(float* __restrict__ dotPart) {
    const size_t off = ((size_t)blockIdx.x * 256 + threadIdx.x) * 4;   // < 2^20
    float4 p0 = *(const float4*)&dotPart[off];
    float4 p1 = *(const float4*)&dotPart[(1ull << 20) + off];
    float4 p2 = *(const float4*)&dotPart[(2ull << 20) + off];
    float4 p3 = *(const float4*)&dotPart[(3ull << 20) + off];
    float4 p4 = *(const float4*)&dotPart[(4ull << 20) + off];
    float4 p5 = *(const float4*)&dotPart[(5ull << 20) + off];
    float4 p6 = *(const float4*)&dotPart[(6ull << 20) + off];
    float4 p7 = *(const float4*)&dotPart[(7ull << 20) + off];
    float4 s;
    s.x = ((p0.x + p1.x) + (p2.x + p3.x)) + ((p4.x + p5.x) + (p6.x + p7.x));
    s.y = ((p0.y + p1.y) + (p2.y + p3.y)) + ((p4.y + p5.y) + (p6.y + p7.y));
    s.z = ((p0.z + p1.z) + (p2.z + p3.z)) + ((p4.z + p5.z) + (p6.z + p7.z));
    s.w = ((p0.w + p1.w) + (p2.w + p3.w)) + ((p4.w + p5.w) + (p6.w + p7.w));
    *(float4*)&dotPart[off] = s;
}

// ---------------------------------------------------------------------------
// select: one block per row. Read 4 KB of the summed plane, coarse cosines,
// single-pass top-2 per partition, threshold candidate ballot. Trusted
// (row,zz): write w01/i01, hdr=0. Untrusted: hdr=cnt + candidate list
// (direct-indexed, NO global atomics).
__global__ __launch_bounds__(256) void select_k(const float* __restrict__ dotSum,
                                                const float* __restrict__ normP,
                                                const float* __restrict__ normK,
                                                const int* __restrict__ colidx,
                                                const int* __restrict__ n0p,
                                                float* __restrict__ w01,   // [2][N][2]
                                                int* __restrict__ i01,     // [2][N][2]
                                                int* __restrict__ wl_hdr,  // [2N]
                                                int* __restrict__ wl_cand) { // [2N][16]
    __shared__ float sr_v1[2][4], sr_v2[2][4];
    __shared__ int   sr_s1[2][4], sr_s2[2][4];
    __shared__ int   s_cnt[2];
    __shared__ int   s_cand[2][16];

    const int row = blockIdx.x;
    const int t   = threadIdx.x;
    const int wave = t >> 6, lane = t & 63;
    const int n0 = *n0p;
    const float nr = normP[row];

    if (t < 2) s_cnt[t] = 0;

    float4 dv = *(const float4*)&dotSum[(size_t)row * N_TOT + 4 * t];

    // coarse cosines for my 4 compacted slots
    float cv[4];
    #pragma unroll
    for (int e = 0; e < 4; e++) {
        int s = 4 * t + e;
        int gj = colidx[s];
        float nb = (s < n0) ? normK[gj] : normP[gj];
        float d  = (e == 0) ? dv.x : (e == 1) ? dv.y : (e == 2) ? dv.z : dv.w;
        cv[e] = d * rsqrtf(nr * nb);
    }

    // single-pass wave-local top-2 per partition (no barriers inside)
    #pragma unroll
    for (int zz = 0; zz < 2; zz++) {
        float v1 = -INFINITY, v2 = -INFINITY;
        int   s1 = 0x7FFFFFFF, s2 = 0x7FFFFFFF;
        #pragma unroll
        for (int e = 0; e < 4; e++) {
            int s = 4 * t + e;
            bool inz = zz ? (s >= n0) : (s < n0);
            if (inz) ins2(cv[e], s, v1, s1, v2, s2);
        }
        #pragma unroll
        for (int off = 32; off > 0; off >>= 1) {
            float o1 = __shfl_xor(v1, off); int q1 = __shfl_xor(s1, off);
            float o2 = __shfl_xor(v2, off); int q2 = __shfl_xor(s2, off);
            ins2(o1, q1, v1, s1, v2, s2);
            ins2(o2, q2, v1, s1, v2, s2);
        }
        if (lane == 0) {
            sr_v1[zz][wave] = v1; sr_s1[zz][wave] = s1;
            sr_v2[zz][wave] = v2; sr_s2[zz][wave] = s2;
        }
    }
    __syncthreads();

    // cross-wave merge (uniform in all threads) + threshold candidate ballot
    float m1z[2], m2z[2]; int b1z[2], b2z[2];
    #pragma unroll
    for (int zz = 0; zz < 2; zz++) {
        float m1 = -INFINITY, m2 = -INFINITY;
        int   b1 = 0x7FFFFFFF, b2 = 0x7FFFFFFF;
        #pragma unroll
        for (int w = 0; w < 4; w++) {
            ins2(sr_v1[zz][w], sr_s1[zz][w], m1, b1, m2, b2);
            ins2(sr_v2[zz][w], sr_s2[zz][w], m1, b1, m2, b2);
        }
        m1z[zz] = m1; m2z[zz] = m2; b1z[zz] = b1; b2z[zz] = b2;
        const float thr = m2 - T_MARGIN;
        #pragma unroll
        for (int e = 0; e < 4; e++) {
            int s = 4 * t + e;
            bool inz = zz ? (s >= n0) : (s < n0);
            if (inz && cv[e] > thr) {
                int idx = atomicAdd(&s_cnt[zz], 1);   // shared-mem atomic only
                if (idx < 16) s_cand[zz][idx] = s;    // >16 cands: graceful cap
            }
        }
    }
    __syncthreads();

    bool need[2]; int cntz[2];
    #pragma unroll
    for (int zz = 0; zz < 2; zz++) {
        const int cnt = min(s_cnt[zz], 16);
        cntz[zz] = cnt;
        const bool trusted = (s_cnt[zz] == 2) && (m1z[zz] - m2z[zz] > T_MARGIN);
        need[zz] = !trusted;
        if (t == 0) {
            wl_hdr[2 * row + zz] = trusted ? 0 : cnt;
            if (trusted) {
                int base = (zz * N_TOT + row) * 2;
                w01[base]     = m1z[zz];
                w01[base + 1] = m2z[zz];
                i01[base]     = colidx[b1z[zz]];
                i01[base + 1] = colidx[b2z[zz]];
            }
        }
    }
    __syncthreads();

    #pragma unroll
    for (int zz = 0; zz < 2; zz++)
        if (need[zz] && t < cntz[zz])
            wl_cand[(2 * row + zz) * 16 + t] = s_cand[zz][t];
}

// ---------------------------------------------------------------------------
// refine2: grid 2048, block = (row,zz) item; instant exit when hdr==0.
// Reconstruct the exact A row in LDS, 8 parallel 32-lane candidate dots
// (two passes if cnt>8), exact top-2 with global-index tie-break.
__global__ __launch_bounds__(256) void refine2(const unsigned short* __restrict__ Phi,
                                               const char* __restrict__ Plo,
                                               const unsigned short* __restrict__ Khi,
                                               const char* __restrict__ Klo,
                                               const float* __restrict__ normP,
                                               const float* __restrict__ normK,
                                               const int* __restrict__ colidx,
                                               const int* __restrict__ n0p,
                                               const int* __restrict__ wl_hdr,
                                               const int* __restrict__ wl_cand,
                                               float* __restrict__ w01,
                                               int* __restrict__ i01) {
    __shared__ float sAf[C_DIM];     // 16 KB exact A row
    __shared__ float s_rcv[16];
    __shared__ int   s_rcj[16];

    const int item = blockIdx.x;
    const int cnt  = wl_hdr[item];
    if (cnt == 0) return;            // trusted -> nothing to do

    const int row = item >> 1;
    const int zz  = item & 1;
    const int t   = threadIdx.x;
    const int grp = t >> 5, l32 = t & 31;
    const int n0 = *n0p;
    const float nr = normP[row];

    // reconstruct exact A row
    {
        const unsigned short* Ah = Phi + (size_t)row * C_DIM;
        const char*           Al = Plo + (size_t)row * C_DIM;
        #pragma unroll
        for (int s = 0; s < 2; s++) {
            int c = t * 16 + s * 8;
            ushort8 hb = *(const ushort8*)&Ah[c];
            schar8  lb = *(const schar8*)&Al[c];
            #pragma unroll
            for (int e = 0; e < 8; e++) sAf[c + e] = h2f(hb[e]) + lo_dec(lb[e], hb[e]);
        }
    }
    __syncthreads();

    #pragma unroll
    for (int p = 0; p < 2; p++) {
        if (p == 1 && cnt <= 8) break;          // uniform
        const int q = grp + 8 * p;
        float acc = 0.0f;
        int gj = 0; float nb = 1.0f;
        if (q < cnt) {
            const int cs = wl_cand[item * 16 + q];
            gj = colidx[cs];
            nb = (cs < n0) ? normK[gj] : normP[gj];
            const unsigned short* bh_row = ((cs < n0) ? Khi : Phi) + (size_t)gj * C_DIM;
            const char*           bl_row = ((cs < n0) ? Klo : Plo) + (size_t)gj * C_DIM;
            #pragma unroll 4
            for (int it = 0; it < 16; it++) {
                int c = it * 256 + l32 * 8;
                ushort8 hb = *(const ushort8*)&bh_row[c];
                schar8  lb = *(const schar8*)&bl_row[c];
                #pragma unroll
                for (int e = 0; e < 8; e++)
                    acc = fmaf(sAf[c + e], h2f(hb[e]) + lo_dec(lb[e], hb[e]), acc);
            }
        }
        #pragma unroll
        for (int off = 16; off > 0; off >>= 1) acc += __shfl_xor(acc, off);
        if (l32 == 0 && q < cnt) {
            s_rcv[q] = acc * rsqrtf(nr * nb);
            s_rcj[q] = gj;
        }
    }
    __syncthreads();

    if (t == 0) {
        float v1 = -INFINITY, v2 = -INFINITY;
        int   j1 = 0x7FFFFFFF, j2 = 0x7FFFFFFF;
        for (int q = 0; q < cnt; q++) {
            float cvx = s_rcv[q];
            int   j   = s_rcj[q];
            if (cvx > v1 || (cvx == v1 && j < j1)) {
                v2 = v1; j2 = j1; v1 = cvx; j1 = j;
            } else if (cvx > v2 || (cvx == v2 && j < j2)) {
                v2 = cvx; j2 = j;
            }
        }
        if (j1 == 0x7FFFFFFF) j1 = 0;   // degenerate-partition guard
        if (j2 == 0x7FFFFFFF) j2 = j1;
        int base = (zz * N_TOT + row) * 2;
        w01[base]     = v1;
        w01[base + 1] = v2;
        i01[base]     = j1;
        i01[base + 1] = j2;
    }
}

// ---------------------------------------------------------------------------
// means_k: single block. Reduce masked means of the 4 weight series over w01
// (16 KB), softmax, write wts[4].
__global__ __launch_bounds__(256) void means_k(const float* __restrict__ flag,
                                               const float* __restrict__ w01,
                                               float* __restrict__ wts) {
    __shared__ float red[5][4];
    const int t = threadIdx.x;
    const int wave = t >> 6, lane = t & 63;

    float pm[5] = {};
    #pragma unroll
    for (int e = 0; e < 4; e++) {
        int n = 4 * t + e;
        float m = flag[n];
        pm[0] += m;
        pm[1] += m * w01[n * 2 + 0];
        pm[2] += m * w01[n * 2 + 1];
        pm[3] += m * w01[2 * N_TOT + n * 2 + 0];
        pm[4] += m * w01[2 * N_TOT + n * 2 + 1];
    }
    #pragma unroll
    for (int i = 0; i < 5; i++)
        #pragma unroll
        for (int off = 32; off > 0; off >>= 1)
            pm[i] += __shfl_xor(pm[i], off);
    if (lane == 0) {
        #pragma unroll
        for (int i = 0; i < 5; i++) red[i][wave] = pm[i];
    }
    __syncthreads();
    if (t == 0) {
        float tot[5];
        #pragma unroll
        for (int i = 0; i < 5; i++)
            tot[i] = red[i][0] + red[i][1] + red[i][2] + red[i][3];
        float inv = 1.0f / tot[0];
        float mv[4] = {tot[1] * inv, tot[2] * inv, tot[3] * inv, tot[4] * inv};
        float mx = fmaxf(fmaxf(mv[0], mv[1]), fmaxf(mv[2], mv[3]));
        float e[4], s = 0.0f;
        #pragma unroll
        for (int q = 0; q < 4; q++) { e[q] = expf(mv[q] - mx); s += e[q]; }
        #pragma unroll
        for (int q = 0; q < 4; q++) wts[q] = e[q] / s;
    }
}

// ---------------------------------------------------------------------------
// output: read precomputed wts, copy generated & known (float4),
// rtn = weighted gather. grid (4096), block 256.
__global__ __launch_bounds__(256) void output_kernel(const float* __restrict__ G,
                                                     const float* __restrict__ Kn,
                                                     const float* __restrict__ flag,
                                                     const float* __restrict__ w01,
                                                     const int* __restrict__ i01,
                                                     const float* __restrict__ wts,
                                                     float* __restrict__ out) {
    __shared__ float swts[4];
    const int c  = blockIdx.x;
    const int t  = threadIdx.x;
    const int n4 = t * 4;

    if (t < 4) swts[t] = wts[t];
    __syncthreads();
    const float w0 = swts[0], w1 = swts[1], w2 = swts[2], w3 = swts[3];

    float4 fv = *(const float4*)&flag[n4];
    const float fa[4] = {fv.x, fv.y, fv.z, fv.w};

    float4 gv = *(const float4*)&G[c * N_TOT + n4];
    float4 kv = *(const float4*)&Kn[c * N_TOT + n4];
    *(float4*)&out[c * N_TOT + n4] = gv;
    *(float4*)&out[C_DIM * N_TOT + c * N_TOT + n4] = kv;

    float val[4];
    #pragma unroll
    for (int e = 0; e < 4; e++) {
        int n = n4 + e;
        float v = 0.0f;
        if (fa[e] == 1.0f) {
            int c00 = i01[n * 2 + 0];
            int c01 = i01[n * 2 + 1];
            int c10 = i01[2 * N_TOT + n * 2 + 0];
            int c11 = i01[2 * N_TOT + n * 2 + 1];
            v = w0 * Kn[c * N_TOT + c00] + w1 * Kn[c * N_TOT + c01]
              + w2 * G[c * N_TOT + c10]  + w3 * G[c * N_TOT + c11];
        }
        if (n == 0) {
            bool m0 = (flag[0] == 1.0f);
            int c00 = i01[0], c01 = i01[1];
            int c10 = i01[2 * N_TOT], c11 = i01[2 * N_TOT + 1];
            float kn0 = Kn[c * N_TOT];
            float g0  = G[c * N_TOT];
            if (!(m0 && c00 == 0)) v += w0 * kn0;
            if (!(m0 && c01 == 0)) v += w1 * kn0;
            if (!(m0 && c10 == 0)) v += w2 * g0;
            if (!(m0 && c11 == 0)) v += w3 * g0;
        }
        val[e] = v;
    }
    *(float4*)&out[2 * C_DIM * N_TOT + c * N_TOT + n4] =
        make_float4(val[0], val[1], val[2], val[3]);
}

// ---------------------------------------------------------------------------
extern "C" void kernel_launch(void* const* d_in, const int* in_sizes, int n_in,
                              void* d_out, int out_size, void* d_ws, size_t ws_size,
                              hipStream_t stream) {
    const float* G    = (const float*)d_in[0];
    const float* Kn   = (const float*)d_in[1];
    const float* flag = (const float*)d_in[2];
    float* out = (float*)d_out;

    // ws layout (~56.5 MB, same footprint class as the round-2 kernel that
    // passed; sum8 accumulates in place so no extra plane is needed)
    char* p = (char*)d_ws;
    unsigned short* Phi = (unsigned short*)p;  p += (size_t)N_TOT * C_DIM * 2;  // 8 MB
    unsigned short* Khi = (unsigned short*)p;  p += (size_t)N_TOT * C_DIM * 2;  // 8 MB
    char* Plo = p;                             p += (size_t)N_TOT * C_DIM;      // 4 MB
    char* Klo = p;                             p += (size_t)N_TOT * C_DIM;      // 4 MB
    float* dotPart = (float*)p;                p += (size_t)8 * N_TOT * N_TOT * 4; // 32 MB
    float* normP   = (float*)p;                p += N_TOT * 4;
    float* normK   = (float*)p;                p += N_TOT * 4;
    float* wts     = (float*)p;                p += 16;
    float* w01     = (float*)p;                p += 4 * N_TOT * 4;
    int*   i01     = (int*)p;                  p += 4 * N_TOT * 4;
    int*   colidx  = (int*)p;                  p += N_TOT * 4;
    int*   n0p     = (int*)p;                  p += 16;
    int*   wl_hdr  = (int*)p;                  p += 2 * N_TOT * 4;
    int*   wl_cand = (int*)p;

    // zero only the atomically-accumulated norms (8 KB)
    hipMemsetAsync(normP, 0, 2 * N_TOT * sizeof(float), stream);

    split_norms<<<dim3(64, 16, 2), 256, 0, stream>>>(G, Kn, flag, Phi, Plo, Khi, Klo,
                                                     normP, normK, colidx, n0p);
    gemm_coarse<<<dim3(16, 8, 8), 256, 0, stream>>>(Phi, Khi, colidx, n0p, dotPart);
    sum8<<<1024, 256, 0, stream>>>(dotPart);
    select_k<<<1024, 256, 0, stream>>>(dotPart, normP, normK, colidx, n0p,
                                       w01, i01, wl_hdr, wl_cand);
    refine2<<<2048, 256, 0, stream>>>(Phi, Plo, Khi, Klo, normP, normK, colidx, n0p,
                                      wl_hdr, wl_cand, w01, i01);
    means_k<<<1, 256, 0, stream>>>(flag, w01, wts);
    output_kernel<<<4096, 256, 0, stream>>>(G, Kn, flag, w01, i01, wts, out);
}

// Round 5
// 168.690 us; speedup vs baseline: 1.1559x; 1.0665x over previous
//
#include <hip/hip_runtime.h>
#include <hip/hip_bf16.h>
#include <math.h>

#define N_TOT 1024
#define C_DIM 4096
#define T_MARGIN 3e-4f   // coarse fp16 cosine err sigma ~6e-6; 3e-4 = ~50 sigma

typedef __attribute__((ext_vector_type(8))) _Float16 half8;
typedef __attribute__((ext_vector_type(8))) unsigned short ushort8;
typedef __attribute__((ext_vector_type(8))) char schar8;
typedef __attribute__((ext_vector_type(4))) float floatx4;

__device__ inline unsigned short f2h(float v) {
    _Float16 h = (_Float16)v;
    return __builtin_bit_cast(unsigned short, h);
}
__device__ inline float h2f(unsigned short u) {
    return (float)__builtin_bit_cast(_Float16, u);
}
// int8 residual with exponent borrowed from the fp16 hi part (err ~ulp/480).
__device__ inline char lo_enc(float v, unsigned short h) {
    int e = (h >> 10) & 31;
    float lo = v - h2f(h);
    float q = rintf(lo * 240.0f * __uint_as_float((unsigned)(152 - e) << 23));
    q = fmaxf(-127.0f, fminf(127.0f, q));
    return (char)(int)q;
}
__device__ inline float lo_dec(char q, unsigned short h) {
    int e = (h >> 10) & 31;
    return (float)q * __uint_as_float((unsigned)(e + 102) << 23) * (1.0f / 240.0f);
}

// lexicographic (value desc, index asc) insert into a sorted top-2 pair
__device__ inline void ins2(float v, int s, float& v1, int& s1, float& v2, int& s2) {
    if (v > v1 || (v == v1 && s < s1)) { v2 = v1; s2 = s1; v1 = v; s1 = s; }
    else if (v > v2 || (v == v2 && s < s2)) { v2 = v; s2 = s; }
}

// ---------------------------------------------------------------------------
// split+transpose+norms: X (C,N) fp32 -> Xhi[n][c] fp16, Xlo[n][c] int8;
// normX[n] += sum_c x^2 (atomic, pre-zeroed). Block (0,0,0) additionally
// computes the flag compaction (colidx, n0). grid (64, 16, 2).
__global__ __launch_bounds__(256) void split_norms(const float* __restrict__ G,
                                                   const float* __restrict__ Kn,
                                                   const float* __restrict__ flag,
                                                   unsigned short* __restrict__ Phi,
                                                   char* __restrict__ Plo,
                                                   unsigned short* __restrict__ Khi,
                                                   char* __restrict__ Klo,
                                                   float* __restrict__ normP,
                                                   float* __restrict__ normK,
                                                   int* __restrict__ colidx,
                                                   int* __restrict__ n0p) {
    const int z = blockIdx.z;
    const float* X = z ? Kn : G;
    unsigned short* Xhi = z ? Khi : Phi;
    char* Xlo = z ? Klo : Plo;
    float* normX = z ? normK : normP;

    __shared__ float tile[64 * 65];
    __shared__ float np[256];
    const int t  = threadIdx.x;
    const int c0 = blockIdx.x * 64;
    const int n0 = blockIdx.y * 64;

    float s2 = 0.0f;
    #pragma unroll
    for (int s = 0; s < 16; s++) {
        int c_loc = s * 4 + (t >> 6);
        int n_loc = t & 63;
        float v = X[(c0 + c_loc) * N_TOT + n0 + n_loc];
        tile[c_loc * 65 + n_loc] = v;
        s2 = fmaf(v, v, s2);
    }
    np[t] = s2;
    __syncthreads();

    if (t < 64) {
        float tot = np[t] + np[t + 64] + np[t + 128] + np[t + 192];
        atomicAdd(&normX[n0 + t], tot);
    }

    // encode+store: each thread handles 8 consecutive c's -> 16B hi / 8B lo stores
    #pragma unroll
    for (int s = 0; s < 2; s++) {
        int n_loc = s * 32 + (t >> 3);
        int c8    = (t & 7) * 8;
        unsigned short h[8]; char l[8];
        #pragma unroll
        for (int e = 0; e < 8; e++) {
            float v = tile[(c8 + e) * 65 + n_loc];
            h[e] = f2h(v);
            l[e] = lo_enc(v, h[e]);
        }
        size_t base = (size_t)(n0 + n_loc) * C_DIM + c0 + c8;
        ushort8 hv; schar8 lv;
        #pragma unroll
        for (int e = 0; e < 8; e++) { hv[e] = h[e]; lv[e] = l[e]; }
        *(ushort8*)&Xhi[base] = hv;
        *(schar8*)&Xlo[base]  = lv;
    }

    // ---- embedded flag scan (block (0,0,0) only; block-uniform branch) ----
    if (blockIdx.x == 0 && blockIdx.y == 0 && blockIdx.z == 0) {
        __shared__ int cz[256];
        __shared__ int co[256];
        float4 fv = *(const float4*)&flag[4 * t];
        int f[4] = {fv.x == 0.0f, fv.y == 0.0f, fv.z == 0.0f, fv.w == 0.0f};
        int nz = f[0] + f[1] + f[2] + f[3];
        cz[t] = nz; co[t] = 4 - nz;
        __syncthreads();
        for (int off = 1; off < 256; off <<= 1) {
            int vz = (t >= off) ? cz[t - off] : 0;
            int vo = (t >= off) ? co[t - off] : 0;
            __syncthreads();
            cz[t] += vz; co[t] += vo;
            __syncthreads();
        }
        const int fn0 = cz[255];
        int zs = cz[t] - nz;
        int os = fn0 + co[t] - (4 - nz);
        #pragma unroll
        for (int e = 0; e < 4; e++) {
            int j = 4 * t + e;
            if (f[e]) colidx[zs++] = j;
            else      colidx[os++] = j;
        }
        if (t == 0) *n0p = fn0;
    }
}

// ---------------------------------------------------------------------------
// coarse fp16 MFMA GEMM vs virtually-compacted B (slot s -> row colidx[s] of
// (s<n0 ? K : P)). 64x128 tile, BK=64, K-split 8 -> grid (16,8,8) = 1024
// blocks, 24 KB LDS, 4 blocks/CU. PLAIN STORES to per-z partial planes
// (each element written once -> no atomics, no zeroing).
__global__ __launch_bounds__(256, 4) void gemm_coarse(const unsigned short* __restrict__ Phi,
                                                      const unsigned short* __restrict__ Khi,
                                                      const int* __restrict__ colidx,
                                                      const int* __restrict__ n0p,
                                                      float* __restrict__ dotPart) {
    __shared__ unsigned short sA[64 * 64];    // 8 KB
    __shared__ unsigned short sB[128 * 64];   // 16 KB

    const int t    = threadIdx.x;
    const int wave = t >> 6, lane = t & 63;
    const int wm   = wave >> 1, wn = wave & 1;
    const int quad = lane >> 4, lrow = lane & 15;
    const int ib = blockIdx.x * 64, jb = blockIdx.y * 128;
    const int bz = blockIdx.z;
    const int k_beg = bz * 512;
    const int n0 = *n0p;

    const int srow = t >> 3;            // 0..31
    const int g    = (t & 7) ^ (srow & 7);

    const unsigned short* gA[2];
    gA[0] = Phi + (size_t)(ib + srow) * C_DIM + g * 8;
    gA[1] = gA[0] + (size_t)32 * C_DIM;
    const unsigned short* gB[4];
    #pragma unroll
    for (int q = 0; q < 4; q++) {
        int s = jb + q * 32 + srow;
        int row = colidx[s];
        const unsigned short* src = (s < n0) ? Khi : Phi;
        gB[q] = src + (size_t)row * C_DIM + g * 8;
    }

    floatx4 acc[2][4] = {};

    for (int k0 = k_beg; k0 < k_beg + 512; k0 += 64) {
        #pragma unroll
        for (int q = 0; q < 2; q++)
            __builtin_amdgcn_global_load_lds(
                (const __attribute__((address_space(1))) void*)(gA[q] + k0),
                (__attribute__((address_space(3))) void*)((char*)sA + q * 4096 + t * 16), 16, 0, 0);
        #pragma unroll
        for (int q = 0; q < 4; q++)
            __builtin_amdgcn_global_load_lds(
                (const __attribute__((address_space(1))) void*)(gB[q] + k0),
                (__attribute__((address_space(3))) void*)((char*)sB + q * 4096 + t * 16), 16, 0, 0);
        __syncthreads();

        #pragma unroll
        for (int kk = 0; kk < 2; kk++) {
            const int gk = kk * 4 + quad;
            half8 a[2], b[4];
            #pragma unroll
            for (int ti = 0; ti < 2; ti++) {
                int m = wm * 32 + ti * 16 + lrow;
                a[ti] = *(const half8*)&sA[m * 64 + ((gk ^ (m & 7)) << 3)];
            }
            #pragma unroll
            for (int tj = 0; tj < 4; tj++) {
                int n = wn * 64 + tj * 16 + lrow;
                b[tj] = *(const half8*)&sB[n * 64 + ((gk ^ (n & 7)) << 3)];
            }
            #pragma unroll
            for (int ti = 0; ti < 2; ti++)
                #pragma unroll
                for (int tj = 0; tj < 4; tj++)
                    acc[ti][tj] = __builtin_amdgcn_mfma_f32_16x16x32_f16(a[ti], b[tj], acc[ti][tj], 0, 0, 0);
        }
        __syncthreads();
    }

    // plain stores into this z's private plane. C/D: col=lane&15, row=quad*4+reg
    float* outp = dotPart + ((size_t)bz << 20);
    #pragma unroll
    for (int tj = 0; tj < 4; tj++) {
        int j = jb + wn * 64 + tj * 16 + lrow;
        #pragma unroll
        for (int ti = 0; ti < 2; ti++) {
            #pragma unroll
            for (int reg = 0; reg < 4; reg++) {
                int i = ib + wm * 32 + ti * 16 + quad * 4 + reg;
                outp[i * N_TOT + j] = acc[ti][tj][reg];
            }
        }
    }
}

// ---------------------------------------------------------------------------
// select: one block per row. Register-sum the 8 K-split planes (explicit
// parallel loads, NO separate sum kernel, NO global atomics), coarse cosines,
// single-pass top-2 per partition, threshold candidate ballot. Trusted
// (row,zz): write w01/i01, hdr=0. Untrusted: hdr=cnt + candidate list
// (direct-indexed).
__global__ __launch_bounds__(256) void select_k(const float* __restrict__ dotPart,
                                                const float* __restrict__ normP,
                                                const float* __restrict__ normK,
                                                const int* __restrict__ colidx,
                                                const int* __restrict__ n0p,
                                                float* __restrict__ w01,   // [2][N][2]
                                                int* __restrict__ i01,     // [2][N][2]
                                                int* __restrict__ wl_hdr,  // [2N]
                                                int* __restrict__ wl_cand) { // [2N][16]
    __shared__ float sr_v1[2][4], sr_v2[2][4];
    __shared__ int   sr_s1[2][4], sr_s2[2][4];
    __shared__ int   s_cnt[2];
    __shared__ int   s_cand[2][16];

    const int row = blockIdx.x;
    const int t   = threadIdx.x;
    const int wave = t >> 6, lane = t & 63;
    const int n0 = *n0p;
    const float nr = normP[row];

    if (t < 2) s_cnt[t] = 0;

    // 8-plane register sum (loads issued in parallel)
    const float* base = dotPart + (size_t)row * N_TOT + 4 * t;
    float4 p0 = *(const float4*)(base);
    float4 p1 = *(const float4*)(base + (1ull << 20));
    float4 p2 = *(const float4*)(base + (2ull << 20));
    float4 p3 = *(const float4*)(base + (3ull << 20));
    float4 p4 = *(const float4*)(base + (4ull << 20));
    float4 p5 = *(const float4*)(base + (5ull << 20));
    float4 p6 = *(const float4*)(base + (6ull << 20));
    float4 p7 = *(const float4*)(base + (7ull << 20));
    float4 dv;
    dv.x = ((p0.x + p1.x) + (p2.x + p3.x)) + ((p4.x + p5.x) + (p6.x + p7.x));
    dv.y = ((p0.y + p1.y) + (p2.y + p3.y)) + ((p4.y + p5.y) + (p6.y + p7.y));
    dv.z = ((p0.z + p1.z) + (p2.z + p3.z)) + ((p4.z + p5.z) + (p6.z + p7.z));
    dv.w = ((p0.w + p1.w) + (p2.w + p3.w)) + ((p4.w + p5.w) + (p6.w + p7.w));

    // coarse cosines for my 4 compacted slots
    float cv[4];
    #pragma unroll
    for (int e = 0; e < 4; e++) {
        int s = 4 * t + e;
        int gj = colidx[s];
        float nb = (s < n0) ? normK[gj] : normP[gj];
        float d  = (e == 0) ? dv.x : (e == 1) ? dv.y : (e == 2) ? dv.z : dv.w;
        cv[e] = d * rsqrtf(nr * nb);
    }

    // single-pass wave-local top-2 per partition (no barriers inside)
    #pragma unroll
    for (int zz = 0; zz < 2; zz++) {
        float v1 = -INFINITY, v2 = -INFINITY;
        int   s1 = 0x7FFFFFFF, s2 = 0x7FFFFFFF;
        #pragma unroll
        for (int e = 0; e < 4; e++) {
            int s = 4 * t + e;
            bool inz = zz ? (s >= n0) : (s < n0);
            if (inz) ins2(cv[e], s, v1, s1, v2, s2);
        }
        #pragma unroll
        for (int off = 32; off > 0; off >>= 1) {
            float o1 = __shfl_xor(v1, off); int q1 = __shfl_xor(s1, off);
            float o2 = __shfl_xor(v2, off); int q2 = __shfl_xor(s2, off);
            ins2(o1, q1, v1, s1, v2, s2);
            ins2(o2, q2, v1, s1, v2, s2);
        }
        if (lane == 0) {
            sr_v1[zz][wave] = v1; sr_s1[zz][wave] = s1;
            sr_v2[zz][wave] = v2; sr_s2[zz][wave] = s2;
        }
    }
    __syncthreads();

    // cross-wave merge (uniform in all threads) + threshold candidate ballot
    float m1z[2], m2z[2]; int b1z[2], b2z[2];
    #pragma unroll
    for (int zz = 0; zz < 2; zz++) {
        float m1 = -INFINITY, m2 = -INFINITY;
        int   b1 = 0x7FFFFFFF, b2 = 0x7FFFFFFF;
        #pragma unroll
        for (int w = 0; w < 4; w++) {
            ins2(sr_v1[zz][w], sr_s1[zz][w], m1, b1, m2, b2);
            ins2(sr_v2[zz][w], sr_s2[zz][w], m1, b1, m2, b2);
        }
        m1z[zz] = m1; m2z[zz] = m2; b1z[zz] = b1; b2z[zz] = b2;
        const float thr = m2 - T_MARGIN;
        #pragma unroll
        for (int e = 0; e < 4; e++) {
            int s = 4 * t + e;
            bool inz = zz ? (s >= n0) : (s < n0);
            if (inz && cv[e] > thr) {
                int idx = atomicAdd(&s_cnt[zz], 1);   // shared-mem atomic only
                if (idx < 16) s_cand[zz][idx] = s;    // >16 cands: graceful cap
            }
        }
    }
    __syncthreads();

    bool need[2]; int cntz[2];
    #pragma unroll
    for (int zz = 0; zz < 2; zz++) {
        const int cnt = min(s_cnt[zz], 16);
        cntz[zz] = cnt;
        const bool trusted = (s_cnt[zz] == 2) && (m1z[zz] - m2z[zz] > T_MARGIN);
        need[zz] = !trusted;
        if (t == 0) {
            wl_hdr[2 * row + zz] = trusted ? 0 : cnt;
            if (trusted) {
                int base2 = (zz * N_TOT + row) * 2;
                w01[base2]     = m1z[zz];
                w01[base2 + 1] = m2z[zz];
                i01[base2]     = colidx[b1z[zz]];
                i01[base2 + 1] = colidx[b2z[zz]];
            }
        }
    }
    __syncthreads();

    #pragma unroll
    for (int zz = 0; zz < 2; zz++)
        if (need[zz] && t < cntz[zz])
            wl_cand[(2 * row + zz) * 16 + t] = s_cand[zz][t];
}

// ---------------------------------------------------------------------------
// refine2: grid 2048, block = (row,zz) item; instant exit when hdr==0.
// Reconstruct the exact A row in LDS, 8 parallel 32-lane candidate dots
// (two passes if cnt>8), exact top-2 with global-index tie-break.
__global__ __launch_bounds__(256) void refine2(const unsigned short* __restrict__ Phi,
                                               const char* __restrict__ Plo,
                                               const unsigned short* __restrict__ Khi,
                                               const char* __restrict__ Klo,
                                               const float* __restrict__ normP,
                                               const float* __restrict__ normK,
                                               const int* __restrict__ colidx,
                                               const int* __restrict__ n0p,
                                               const int* __restrict__ wl_hdr,
                                               const int* __restrict__ wl_cand,
                                               float* __restrict__ w01,
                                               int* __restrict__ i01) {
    __shared__ float sAf[C_DIM];     // 16 KB exact A row
    __shared__ float s_rcv[16];
    __shared__ int   s_rcj[16];

    const int item = blockIdx.x;
    const int cnt  = wl_hdr[item];
    if (cnt == 0) return;            // trusted -> nothing to do

    const int row = item >> 1;
    const int zz  = item & 1;
    const int t   = threadIdx.x;
    const int grp = t >> 5, l32 = t & 31;
    const int n0 = *n0p;
    const float nr = normP[row];

    // reconstruct exact A row
    {
        const unsigned short* Ah = Phi + (size_t)row * C_DIM;
        const char*           Al = Plo + (size_t)row * C_DIM;
        #pragma unroll
        for (int s = 0; s < 2; s++) {
            int c = t * 16 + s * 8;
            ushort8 hb = *(const ushort8*)&Ah[c];
            schar8  lb = *(const schar8*)&Al[c];
            #pragma unroll
            for (int e = 0; e < 8; e++) sAf[c + e] = h2f(hb[e]) + lo_dec(lb[e], hb[e]);
        }
    }
    __syncthreads();

    #pragma unroll
    for (int p = 0; p < 2; p++) {
        if (p == 1 && cnt <= 8) break;          // uniform
        const int q = grp + 8 * p;
        float acc = 0.0f;
        int gj = 0; float nb = 1.0f;
        if (q < cnt) {
            const int cs = wl_cand[item * 16 + q];
            gj = colidx[cs];
            nb = (cs < n0) ? normK[gj] : normP[gj];
            const unsigned short* bh_row = ((cs < n0) ? Khi : Phi) + (size_t)gj * C_DIM;
            const char*           bl_row = ((cs < n0) ? Klo : Plo) + (size_t)gj * C_DIM;
            #pragma unroll 4
            for (int it = 0; it < 16; it++) {
                int c = it * 256 + l32 * 8;
                ushort8 hb = *(const ushort8*)&bh_row[c];
                schar8  lb = *(const schar8*)&bl_row[c];
                #pragma unroll
                for (int e = 0; e < 8; e++)
                    acc = fmaf(sAf[c + e], h2f(hb[e]) + lo_dec(lb[e], hb[e]), acc);
            }
        }
        #pragma unroll
        for (int off = 16; off > 0; off >>= 1) acc += __shfl_xor(acc, off);
        if (l32 == 0 && q < cnt) {
            s_rcv[q] = acc * rsqrtf(nr * nb);
            s_rcj[q] = gj;
        }
    }
    __syncthreads();

    if (t == 0) {
        float v1 = -INFINITY, v2 = -INFINITY;
        int   j1 = 0x7FFFFFFF, j2 = 0x7FFFFFFF;
        for (int q = 0; q < cnt; q++) {
            float cvx = s_rcv[q];
            int   j   = s_rcj[q];
            if (cvx > v1 || (cvx == v1 && j < j1)) {
                v2 = v1; j2 = j1; v1 = cvx; j1 = j;
            } else if (cvx > v2 || (cvx == v2 && j < j2)) {
                v2 = cvx; j2 = j;
            }
        }
        if (j1 == 0x7FFFFFFF) j1 = 0;   // degenerate-partition guard
        if (j2 == 0x7FFFFFFF) j2 = j1;
        int base = (zz * N_TOT + row) * 2;
        w01[base]     = v1;
        w01[base + 1] = v2;
        i01[base]     = j1;
        i01[base + 1] = j2;
    }
}

// ---------------------------------------------------------------------------
// means_k: single block. Reduce masked means of the 4 weight series over w01
// (16 KB), softmax, write wts[4].
__global__ __launch_bounds__(256) void means_k(const float* __restrict__ flag,
                                               const float* __restrict__ w01,
                                               float* __restrict__ wts) {
    __shared__ float red[5][4];
    const int t = threadIdx.x;
    const int wave = t >> 6, lane = t & 63;

    float pm[5] = {};
    #pragma unroll
    for (int e = 0; e < 4; e++) {
        int n = 4 * t + e;
        float m = flag[n];
        pm[0] += m;
        pm[1] += m * w01[n * 2 + 0];
        pm[2] += m * w01[n * 2 + 1];
        pm[3] += m * w01[2 * N_TOT + n * 2 + 0];
        pm[4] += m * w01[2 * N_TOT + n * 2 + 1];
    }
    #pragma unroll
    for (int i = 0; i < 5; i++)
        #pragma unroll
        for (int off = 32; off > 0; off >>= 1)
            pm[i] += __shfl_xor(pm[i], off);
    if (lane == 0) {
        #pragma unroll
        for (int i = 0; i < 5; i++) red[i][wave] = pm[i];
    }
    __syncthreads();
    if (t == 0) {
        float tot[5];
        #pragma unroll
        for (int i = 0; i < 5; i++)
            tot[i] = red[i][0] + red[i][1] + red[i][2] + red[i][3];
        float inv = 1.0f / tot[0];
        float mv[4] = {tot[1] * inv, tot[2] * inv, tot[3] * inv, tot[4] * inv};
        float mx = fmaxf(fmaxf(mv[0], mv[1]), fmaxf(mv[2], mv[3]));
        float e[4], s = 0.0f;
        #pragma unroll
        for (int q = 0; q < 4; q++) { e[q] = expf(mv[q] - mx); s += e[q]; }
        #pragma unroll
        for (int q = 0; q < 4; q++) wts[q] = e[q] / s;
    }
}

// ---------------------------------------------------------------------------
// output: stage rows of G/Kn in LDS (coalesced), copies from the staged
// registers, gather served from LDS; i01 read as int2. grid (4096), block 256.
__global__ __launch_bounds__(256) void output_kernel(const float* __restrict__ G,
                                                     const float* __restrict__ Kn,
                                                     const float* __restrict__ flag,
                                                     const int* __restrict__ i01,
                                                     const float* __restrict__ wts,
                                                     float* __restrict__ out) {
    __shared__ float sG[N_TOT];
    __shared__ float sKn[N_TOT];
    __shared__ float swts[4];
    const int c  = blockIdx.x;
    const int t  = threadIdx.x;
    const int n4 = t * 4;

    if (t < 4) swts[t] = wts[t];

    float4 gv = *(const float4*)&G[c * N_TOT + n4];
    float4 kv = *(const float4*)&Kn[c * N_TOT + n4];
    *(float4*)&sG[n4]  = gv;
    *(float4*)&sKn[n4] = kv;
    *(float4*)&out[c * N_TOT + n4] = gv;
    *(float4*)&out[C_DIM * N_TOT + c * N_TOT + n4] = kv;

    float4 fv = *(const float4*)&flag[n4];
    const float fa[4] = {fv.x, fv.y, fv.z, fv.w};
    __syncthreads();

    const float w0 = swts[0], w1 = swts[1], w2 = swts[2], w3 = swts[3];

    float val[4];
    #pragma unroll
    for (int e = 0; e < 4; e++) {
        int n = n4 + e;
        float v = 0.0f;
        if (fa[e] == 1.0f) {
            int2 i0 = *(const int2*)&i01[n * 2];
            int2 i1 = *(const int2*)&i01[2 * N_TOT + n * 2];
            v = w0 * sKn[i0.x] + w1 * sKn[i0.y]
              + w2 * sG[i1.x]  + w3 * sG[i1.y];
        }
        if (n == 0) {
            bool m0 = (flag[0] == 1.0f);
            int2 i0 = *(const int2*)&i01[0];
            int2 i1 = *(const int2*)&i01[2 * N_TOT];
            float kn0 = sKn[0];
            float g0  = sG[0];
            if (!(m0 && i0.x == 0)) v += w0 * kn0;
            if (!(m0 && i0.y == 0)) v += w1 * kn0;
            if (!(m0 && i1.x == 0)) v += w2 * g0;
            if (!(m0 && i1.y == 0)) v += w3 * g0;
        }
        val[e] = v;
    }
    *(float4*)&out[2 * C_DIM * N_TOT + c * N_TOT + n4] =
        make_float4(val[0], val[1], val[2], val[3]);
}

// ---------------------------------------------------------------------------
extern "C" void kernel_launch(void* const* d_in, const int* in_sizes, int n_in,
                              void* d_out, int out_size, void* d_ws, size_t ws_size,
                              hipStream_t stream) {
    const float* G    = (const float*)d_in[0];
    const float* Kn   = (const float*)d_in[1];
    const float* flag = (const float*)d_in[2];
    float* out = (float*)d_out;

    // ws layout (~56.5 MB)
    char* p = (char*)d_ws;
    unsigned short* Phi = (unsigned short*)p;  p += (size_t)N_TOT * C_DIM * 2;  // 8 MB
    unsigned short* Khi = (unsigned short*)p;  p += (size_t)N_TOT * C_DIM * 2;  // 8 MB
    char* Plo = p;                             p += (size_t)N_TOT * C_DIM;      // 4 MB
    char* Klo = p;                             p += (size_t)N_TOT * C_DIM;      // 4 MB
    float* dotPart = (float*)p;                p += (size_t)8 * N_TOT * N_TOT * 4; // 32 MB
    float* normP   = (float*)p;                p += N_TOT * 4;
    float* normK   = (float*)p;                p += N_TOT * 4;
    float* wts     = (float*)p;                p += 16;
    float* w01     = (float*)p;                p += 4 * N_TOT * 4;
    int*   i01     = (int*)p;                  p += 4 * N_TOT * 4;
    int*   colidx  = (int*)p;                  p += N_TOT * 4;
    int*   n0p     = (int*)p;                  p += 16;
    int*   wl_hdr  = (int*)p;                  p += 2 * N_TOT * 4;
    int*   wl_cand = (int*)p;

    // zero only the atomically-accumulated norms (8 KB)
    hipMemsetAsync(normP, 0, 2 * N_TOT * sizeof(float), stream);

    split_norms<<<dim3(64, 16, 2), 256, 0, stream>>>(G, Kn, flag, Phi, Plo, Khi, Klo,
                                                     normP, normK, colidx, n0p);
    gemm_coarse<<<dim3(16, 8, 8), 256, 0, stream>>>(Phi, Khi, colidx, n0p, dotPart);
    select_k<<<1024, 256, 0, stream>>>(dotPart, normP, normK, colidx, n0p,
                                       w01, i01, wl_hdr, wl_cand);
    refine2<<<2048, 256, 0, stream>>>(Phi, Plo, Khi, Klo, normP, normK, colidx, n0p,
                                      wl_hdr, wl_cand, w01, i01);
    means_k<<<1, 256, 0, stream>>>(flag, w01, wts);
    output_kernel<<<4096, 256, 0, stream>>>(G, Kn, flag, i01, wts, out);
}

// Round 6
// 167.325 us; speedup vs baseline: 1.1653x; 1.0082x over previous
//
#include <hip/hip_runtime.h>
#include <hip/hip_bf16.h>
#include <math.h>

#define N_TOT 1024
#define C_DIM 4096
#define T_MARGIN 3e-4f   // coarse fp16 cosine err sigma ~6e-6; 3e-4 = ~50 sigma

typedef __attribute__((ext_vector_type(8))) _Float16 half8;
typedef __attribute__((ext_vector_type(8))) unsigned short ushort8;
typedef __attribute__((ext_vector_type(8))) char schar8;
typedef __attribute__((ext_vector_type(4))) float floatx4;

__device__ inline unsigned short f2h(float v) {
    _Float16 h = (_Float16)v;
    return __builtin_bit_cast(unsigned short, h);
}
__device__ inline float h2f(unsigned short u) {
    return (float)__builtin_bit_cast(_Float16, u);
}
// int8 residual with exponent borrowed from the fp16 hi part (err ~ulp/480).
__device__ inline char lo_enc(float v, unsigned short h) {
    int e = (h >> 10) & 31;
    float lo = v - h2f(h);
    float q = rintf(lo * 240.0f * __uint_as_float((unsigned)(152 - e) << 23));
    q = fmaxf(-127.0f, fminf(127.0f, q));
    return (char)(int)q;
}
__device__ inline float lo_dec(char q, unsigned short h) {
    int e = (h >> 10) & 31;
    return (float)q * __uint_as_float((unsigned)(e + 102) << 23) * (1.0f / 240.0f);
}

// lexicographic (value desc, index asc) insert into a sorted top-2 pair
__device__ inline void ins2(float v, int s, float& v1, int& s1, float& v2, int& s2) {
    if (v > v1 || (v == v1 && s < s1)) { v2 = v1; s2 = s1; v1 = v; s1 = s; }
    else if (v > v2 || (v == v2 && s < s2)) { v2 = v; s2 = s; }
}

// ---------------------------------------------------------------------------
// split+transpose+norms: X (C,N) fp32 -> Xhi[n][c] fp16, Xlo[n][c] int8;
// normX[n] += sum_c x^2 (atomic, pre-zeroed). float4 global loads; norms
// accumulated in the encode phase (per-column partial + shfl over the 8
// lanes sharing a column + 1 atomic/column). Block (0,0,0) additionally
// computes the flag compaction (colidx, n0). grid (64, 16, 2).
__global__ __launch_bounds__(256) void split_norms(const float* __restrict__ G,
                                                   const float* __restrict__ Kn,
                                                   const float* __restrict__ flag,
                                                   unsigned short* __restrict__ Phi,
                                                   char* __restrict__ Plo,
                                                   unsigned short* __restrict__ Khi,
                                                   char* __restrict__ Klo,
                                                   float* __restrict__ normP,
                                                   float* __restrict__ normK,
                                                   int* __restrict__ colidx,
                                                   int* __restrict__ n0p) {
    const int z = blockIdx.z;
    const float* X = z ? Kn : G;
    unsigned short* Xhi = z ? Khi : Phi;
    char* Xlo = z ? Klo : Plo;
    float* normX = z ? normK : normP;

    __shared__ float tile[64 * 65];
    const int t  = threadIdx.x;
    const int c0 = blockIdx.x * 64;
    const int n0 = blockIdx.y * 64;

    // load phase: float4 along n (4 loads/thread instead of 16 scalars)
    #pragma unroll
    for (int s = 0; s < 4; s++) {
        int c_loc = s * 16 + (t >> 4);
        int n4    = (t & 15) * 4;
        float4 v = *(const float4*)&X[(size_t)(c0 + c_loc) * N_TOT + n0 + n4];
        tile[c_loc * 65 + n4 + 0] = v.x;
        tile[c_loc * 65 + n4 + 1] = v.y;
        tile[c_loc * 65 + n4 + 2] = v.z;
        tile[c_loc * 65 + n4 + 3] = v.w;
    }
    __syncthreads();

    // encode + per-column norms: each thread handles 8 consecutive c's of one
    // column; 8 threads (t&7) cover the 64 c's of that column in this block.
    #pragma unroll
    for (int s = 0; s < 2; s++) {
        int n_loc = s * 32 + (t >> 3);
        int c8    = (t & 7) * 8;
        unsigned short h[8]; char l[8];
        float s2 = 0.0f;
        #pragma unroll
        for (int e = 0; e < 8; e++) {
            float v = tile[(c8 + e) * 65 + n_loc];
            s2 = fmaf(v, v, s2);
            h[e] = f2h(v);
            l[e] = lo_enc(v, h[e]);
        }
        s2 += __shfl_xor(s2, 1);
        s2 += __shfl_xor(s2, 2);
        s2 += __shfl_xor(s2, 4);
        if ((t & 7) == 0) atomicAdd(&normX[n0 + n_loc], s2);

        size_t base = (size_t)(n0 + n_loc) * C_DIM + c0 + c8;
        ushort8 hv; schar8 lv;
        #pragma unroll
        for (int e = 0; e < 8; e++) { hv[e] = h[e]; lv[e] = l[e]; }
        *(ushort8*)&Xhi[base] = hv;
        *(schar8*)&Xlo[base]  = lv;
    }

    // ---- embedded flag scan (block (0,0,0) only; block-uniform branch) ----
    if (blockIdx.x == 0 && blockIdx.y == 0 && blockIdx.z == 0) {
        __shared__ int cz[256];
        __shared__ int co[256];
        float4 fv = *(const float4*)&flag[4 * t];
        int f[4] = {fv.x == 0.0f, fv.y == 0.0f, fv.z == 0.0f, fv.w == 0.0f};
        int nz = f[0] + f[1] + f[2] + f[3];
        cz[t] = nz; co[t] = 4 - nz;
        __syncthreads();
        for (int off = 1; off < 256; off <<= 1) {
            int vz = (t >= off) ? cz[t - off] : 0;
            int vo = (t >= off) ? co[t - off] : 0;
            __syncthreads();
            cz[t] += vz; co[t] += vo;
            __syncthreads();
        }
        const int fn0 = cz[255];
        int zs = cz[t] - nz;
        int os = fn0 + co[t] - (4 - nz);
        #pragma unroll
        for (int e = 0; e < 4; e++) {
            int j = 4 * t + e;
            if (f[e]) colidx[zs++] = j;
            else      colidx[os++] = j;
        }
        if (t == 0) *n0p = fn0;
    }
}

// ---------------------------------------------------------------------------
// coarse fp16 MFMA GEMM vs virtually-compacted B (slot s -> row colidx[s] of
// (s<n0 ? K : P)). 128x128 tile, BK=64, K-split 8 -> grid (8,8,8) = 512
// blocks, 32 KB LDS, 2 blocks/CU. 4 waves, each owning a 64x64 quadrant
// (4x4 accs) -> 32 MFMA per K-step per wave (2x the 64x128 tile's intensity).
// PLAIN STORES to per-z partial planes.
__global__ __launch_bounds__(256, 2) void gemm_coarse(const unsigned short* __restrict__ Phi,
                                                      const unsigned short* __restrict__ Khi,
                                                      const int* __restrict__ colidx,
                                                      const int* __restrict__ n0p,
                                                      float* __restrict__ dotPart) {
    __shared__ unsigned short sA[128 * 64];   // 16 KB
    __shared__ unsigned short sB[128 * 64];   // 16 KB

    const int t    = threadIdx.x;
    const int wave = t >> 6, lane = t & 63;
    const int wm   = wave >> 1, wn = wave & 1;
    const int quad = lane >> 4, lrow = lane & 15;
    const int ib = blockIdx.x * 128, jb = blockIdx.y * 128;
    const int bz = blockIdx.z;
    const int k_beg = bz * 512;
    const int n0 = *n0p;

    const int srow = t >> 3;                    // 0..31
    const int g    = (t & 7) ^ (srow & 7);      // q-invariant (32 % 8 == 0)

    // A: rows ib + q*32 + srow, q = 0..3
    const unsigned short* gA0 = Phi + (size_t)(ib + srow) * C_DIM + g * 8;
    // B: compacted slots jb + q*32 + srow
    const unsigned short* gB[4];
    #pragma unroll
    for (int q = 0; q < 4; q++) {
        int s = jb + q * 32 + srow;
        int row = colidx[s];
        const unsigned short* src = (s < n0) ? Khi : Phi;
        gB[q] = src + (size_t)row * C_DIM + g * 8;
    }

    floatx4 acc[4][4] = {};

    for (int k0 = k_beg; k0 < k_beg + 512; k0 += 64) {
        #pragma unroll
        for (int q = 0; q < 4; q++)
            __builtin_amdgcn_global_load_lds(
                (const __attribute__((address_space(1))) void*)(gA0 + (size_t)q * 32 * C_DIM + k0),
                (__attribute__((address_space(3))) void*)((char*)sA + q * 4096 + t * 16), 16, 0, 0);
        #pragma unroll
        for (int q = 0; q < 4; q++)
            __builtin_amdgcn_global_load_lds(
                (const __attribute__((address_space(1))) void*)(gB[q] + k0),
                (__attribute__((address_space(3))) void*)((char*)sB + q * 4096 + t * 16), 16, 0, 0);
        __syncthreads();

        #pragma unroll
        for (int kk = 0; kk < 2; kk++) {
            const int gk = kk * 4 + quad;
            half8 a[4], b[4];
            #pragma unroll
            for (int ti = 0; ti < 4; ti++) {
                int m = wm * 64 + ti * 16 + lrow;
                a[ti] = *(const half8*)&sA[m * 64 + ((gk ^ (m & 7)) << 3)];
            }
            #pragma unroll
            for (int tj = 0; tj < 4; tj++) {
                int n = wn * 64 + tj * 16 + lrow;
                b[tj] = *(const half8*)&sB[n * 64 + ((gk ^ (n & 7)) << 3)];
            }
            #pragma unroll
            for (int ti = 0; ti < 4; ti++)
                #pragma unroll
                for (int tj = 0; tj < 4; tj++)
                    acc[ti][tj] = __builtin_amdgcn_mfma_f32_16x16x32_f16(a[ti], b[tj], acc[ti][tj], 0, 0, 0);
        }
        __syncthreads();
    }

    // plain stores into this z's private plane. C/D: col=lane&15, row=quad*4+reg
    float* outp = dotPart + ((size_t)bz << 20);
    #pragma unroll
    for (int tj = 0; tj < 4; tj++) {
        int j = jb + wn * 64 + tj * 16 + lrow;
        #pragma unroll
        for (int ti = 0; ti < 4; ti++) {
            #pragma unroll
            for (int reg = 0; reg < 4; reg++) {
                int i = ib + wm * 64 + ti * 16 + quad * 4 + reg;
                outp[i * N_TOT + j] = acc[ti][tj][reg];
            }
        }
    }
}

// ---------------------------------------------------------------------------
// select: one block per row. Register-sum the 8 K-split planes, coarse
// cosines, single-pass top-2 per partition, threshold candidate ballot.
// Trusted (row,zz): write w01/i01, hdr=0. Untrusted: hdr=cnt + candidate
// list (direct-indexed, no global atomics).
__global__ __launch_bounds__(256) void select_k(const float* __restrict__ dotPart,
                                                const float* __restrict__ normP,
                                                const float* __restrict__ normK,
                                                const int* __restrict__ colidx,
                                                const int* __restrict__ n0p,
                                                float* __restrict__ w01,   // [2][N][2]
                                                int* __restrict__ i01,     // [2][N][2]
                                                int* __restrict__ wl_hdr,  // [2N]
                                                int* __restrict__ wl_cand) { // [2N][16]
    __shared__ float sr_v1[2][4], sr_v2[2][4];
    __shared__ int   sr_s1[2][4], sr_s2[2][4];
    __shared__ int   s_cnt[2];
    __shared__ int   s_cand[2][16];

    const int row = blockIdx.x;
    const int t   = threadIdx.x;
    const int wave = t >> 6, lane = t & 63;
    const int n0 = *n0p;
    const float nr = normP[row];

    if (t < 2) s_cnt[t] = 0;

    // 8-plane register sum (loads issued in parallel)
    const float* base = dotPart + (size_t)row * N_TOT + 4 * t;
    float4 p0 = *(const float4*)(base);
    float4 p1 = *(const float4*)(base + (1ull << 20));
    float4 p2 = *(const float4*)(base + (2ull << 20));
    float4 p3 = *(const float4*)(base + (3ull << 20));
    float4 p4 = *(const float4*)(base + (4ull << 20));
    float4 p5 = *(const float4*)(base + (5ull << 20));
    float4 p6 = *(const float4*)(base + (6ull << 20));
    float4 p7 = *(const float4*)(base + (7ull << 20));
    float4 dv;
    dv.x = ((p0.x + p1.x) + (p2.x + p3.x)) + ((p4.x + p5.x) + (p6.x + p7.x));
    dv.y = ((p0.y + p1.y) + (p2.y + p3.y)) + ((p4.y + p5.y) + (p6.y + p7.y));
    dv.z = ((p0.z + p1.z) + (p2.z + p3.z)) + ((p4.z + p5.z) + (p6.z + p7.z));
    dv.w = ((p0.w + p1.w) + (p2.w + p3.w)) + ((p4.w + p5.w) + (p6.w + p7.w));

    // coarse cosines for my 4 compacted slots
    float cv[4];
    #pragma unroll
    for (int e = 0; e < 4; e++) {
        int s = 4 * t + e;
        int gj = colidx[s];
        float nb = (s < n0) ? normK[gj] : normP[gj];
        float d  = (e == 0) ? dv.x : (e == 1) ? dv.y : (e == 2) ? dv.z : dv.w;
        cv[e] = d * rsqrtf(nr * nb);
    }

    // single-pass wave-local top-2 per partition (no barriers inside)
    #pragma unroll
    for (int zz = 0; zz < 2; zz++) {
        float v1 = -INFINITY, v2 = -INFINITY;
        int   s1 = 0x7FFFFFFF, s2 = 0x7FFFFFFF;
        #pragma unroll
        for (int e = 0; e < 4; e++) {
            int s = 4 * t + e;
            bool inz = zz ? (s >= n0) : (s < n0);
            if (inz) ins2(cv[e], s, v1, s1, v2, s2);
        }
        #pragma unroll
        for (int off = 32; off > 0; off >>= 1) {
            float o1 = __shfl_xor(v1, off); int q1 = __shfl_xor(s1, off);
            float o2 = __shfl_xor(v2, off); int q2 = __shfl_xor(s2, off);
            ins2(o1, q1, v1, s1, v2, s2);
            ins2(o2, q2, v1, s1, v2, s2);
        }
        if (lane == 0) {
            sr_v1[zz][wave] = v1; sr_s1[zz][wave] = s1;
            sr_v2[zz][wave] = v2; sr_s2[zz][wave] = s2;
        }
    }
    __syncthreads();

    // cross-wave merge (uniform in all threads) + threshold candidate ballot
    float m1z[2], m2z[2]; int b1z[2], b2z[2];
    #pragma unroll
    for (int zz = 0; zz < 2; zz++) {
        float m1 = -INFINITY, m2 = -INFINITY;
        int   b1 = 0x7FFFFFFF, b2 = 0x7FFFFFFF;
        #pragma unroll
        for (int w = 0; w < 4; w++) {
            ins2(sr_v1[zz][w], sr_s1[zz][w], m1, b1, m2, b2);
            ins2(sr_v2[zz][w], sr_s2[zz][w], m1, b1, m2, b2);
        }
        m1z[zz] = m1; m2z[zz] = m2; b1z[zz] = b1; b2z[zz] = b2;
        const float thr = m2 - T_MARGIN;
        #pragma unroll
        for (int e = 0; e < 4; e++) {
            int s = 4 * t + e;
            bool inz = zz ? (s >= n0) : (s < n0);
            if (inz && cv[e] > thr) {
                int idx = atomicAdd(&s_cnt[zz], 1);   // shared-mem atomic only
                if (idx < 16) s_cand[zz][idx] = s;    // >16 cands: graceful cap
            }
        }
    }
    __syncthreads();

    bool need[2]; int cntz[2];
    #pragma unroll
    for (int zz = 0; zz < 2; zz++) {
        const int cnt = min(s_cnt[zz], 16);
        cntz[zz] = cnt;
        const bool trusted = (s_cnt[zz] == 2) && (m1z[zz] - m2z[zz] > T_MARGIN);
        need[zz] = !trusted;
        if (t == 0) {
            wl_hdr[2 * row + zz] = trusted ? 0 : cnt;
            if (trusted) {
                int base2 = (zz * N_TOT + row) * 2;
                w01[base2]     = m1z[zz];
                w01[base2 + 1] = m2z[zz];
                i01[base2]     = colidx[b1z[zz]];
                i01[base2 + 1] = colidx[b2z[zz]];
            }
        }
    }
    __syncthreads();

    #pragma unroll
    for (int zz = 0; zz < 2; zz++)
        if (need[zz] && t < cntz[zz])
            wl_cand[(2 * row + zz) * 16 + t] = s_cand[zz][t];
}

// ---------------------------------------------------------------------------
// refine2: grid 2048, block = (row,zz) item; instant exit when hdr==0.
// Reconstruct the exact A row in LDS, 8 parallel 32-lane candidate dots
// (two passes if cnt>8), exact top-2 with global-index tie-break.
__global__ __launch_bounds__(256) void refine2(const unsigned short* __restrict__ Phi,
                                               const char* __restrict__ Plo,
                                               const unsigned short* __restrict__ Khi,
                                               const char* __restrict__ Klo,
                                               const float* __restrict__ normP,
                                               const float* __restrict__ normK,
                                               const int* __restrict__ colidx,
                                               const int* __restrict__ n0p,
                                               const int* __restrict__ wl_hdr,
                                               const int* __restrict__ wl_cand,
                                               float* __restrict__ w01,
                                               int* __restrict__ i01) {
    __shared__ float sAf[C_DIM];     // 16 KB exact A row
    __shared__ float s_rcv[16];
    __shared__ int   s_rcj[16];

    const int item = blockIdx.x;
    const int cnt  = wl_hdr[item];
    if (cnt == 0) return;            // trusted -> nothing to do

    const int row = item >> 1;
    const int zz  = item & 1;
    const int t   = threadIdx.x;
    const int grp = t >> 5, l32 = t & 31;
    const int n0 = *n0p;
    const float nr = normP[row];

    // reconstruct exact A row
    {
        const unsigned short* Ah = Phi + (size_t)row * C_DIM;
        const char*           Al = Plo + (size_t)row * C_DIM;
        #pragma unroll
        for (int s = 0; s < 2; s++) {
            int c = t * 16 + s * 8;
            ushort8 hb = *(const ushort8*)&Ah[c];
            schar8  lb = *(const schar8*)&Al[c];
            #pragma unroll
            for (int e = 0; e < 8; e++) sAf[c + e] = h2f(hb[e]) + lo_dec(lb[e], hb[e]);
        }
    }
    __syncthreads();

    #pragma unroll
    for (int p = 0; p < 2; p++) {
        if (p == 1 && cnt <= 8) break;          // uniform
        const int q = grp + 8 * p;
        float acc = 0.0f;
        int gj = 0; float nb = 1.0f;
        if (q < cnt) {
            const int cs = wl_cand[item * 16 + q];
            gj = colidx[cs];
            nb = (cs < n0) ? normK[gj] : normP[gj];
            const unsigned short* bh_row = ((cs < n0) ? Khi : Phi) + (size_t)gj * C_DIM;
            const char*           bl_row = ((cs < n0) ? Klo : Plo) + (size_t)gj * C_DIM;
            #pragma unroll 4
            for (int it = 0; it < 16; it++) {
                int c = it * 256 + l32 * 8;
                ushort8 hb = *(const ushort8*)&bh_row[c];
                schar8  lb = *(const schar8*)&bl_row[c];
                #pragma unroll
                for (int e = 0; e < 8; e++)
                    acc = fmaf(sAf[c + e], h2f(hb[e]) + lo_dec(lb[e], hb[e]), acc);
            }
        }
        #pragma unroll
        for (int off = 16; off > 0; off >>= 1) acc += __shfl_xor(acc, off);
        if (l32 == 0 && q < cnt) {
            s_rcv[q] = acc * rsqrtf(nr * nb);
            s_rcj[q] = gj;
        }
    }
    __syncthreads();

    if (t == 0) {
        float v1 = -INFINITY, v2 = -INFINITY;
        int   j1 = 0x7FFFFFFF, j2 = 0x7FFFFFFF;
        for (int q = 0; q < cnt; q++) {
            float cvx = s_rcv[q];
            int   j   = s_rcj[q];
            if (cvx > v1 || (cvx == v1 && j < j1)) {
                v2 = v1; j2 = j1; v1 = cvx; j1 = j;
            } else if (cvx > v2 || (cvx == v2 && j < j2)) {
                v2 = cvx; j2 = j;
            }
        }
        if (j1 == 0x7FFFFFFF) j1 = 0;   // degenerate-partition guard
        if (j2 == 0x7FFFFFFF) j2 = j1;
        int base = (zz * N_TOT + row) * 2;
        w01[base]     = v1;
        w01[base + 1] = v2;
        i01[base]     = j1;
        i01[base + 1] = j2;
    }
}

// ---------------------------------------------------------------------------
// means_k: single block. Reduce masked means of the 4 weight series over w01
// (16 KB), softmax, write wts[4].
__global__ __launch_bounds__(256) void means_k(const float* __restrict__ flag,
                                               const float* __restrict__ w01,
                                               float* __restrict__ wts) {
    __shared__ float red[5][4];
    const int t = threadIdx.x;
    const int wave = t >> 6, lane = t & 63;

    float pm[5] = {};
    #pragma unroll
    for (int e = 0; e < 4; e++) {
        int n = 4 * t + e;
        float m = flag[n];
        pm[0] += m;
        pm[1] += m * w01[n * 2 + 0];
        pm[2] += m * w01[n * 2 + 1];
        pm[3] += m * w01[2 * N_TOT + n * 2 + 0];
        pm[4] += m * w01[2 * N_TOT + n * 2 + 1];
    }
    #pragma unroll
    for (int i = 0; i < 5; i++)
        #pragma unroll
        for (int off = 32; off > 0; off >>= 1)
            pm[i] += __shfl_xor(pm[i], off);
    if (lane == 0) {
        #pragma unroll
        for (int i = 0; i < 5; i++) red[i][wave] = pm[i];
    }
    __syncthreads();
    if (t == 0) {
        float tot[5];
        #pragma unroll
        for (int i = 0; i < 5; i++)
            tot[i] = red[i][0] + red[i][1] + red[i][2] + red[i][3];
        float inv = 1.0f / tot[0];
        float mv[4] = {tot[1] * inv, tot[2] * inv, tot[3] * inv, tot[4] * inv};
        float mx = fmaxf(fmaxf(mv[0], mv[1]), fmaxf(mv[2], mv[3]));
        float e[4], s = 0.0f;
        #pragma unroll
        for (int q = 0; q < 4; q++) { e[q] = expf(mv[q] - mx); s += e[q]; }
        #pragma unroll
        for (int q = 0; q < 4; q++) wts[q] = e[q] / s;
    }
}

// ---------------------------------------------------------------------------
// output: TWO channels per block. Stage both G/Kn rows in LDS (coalesced),
// copies from staged registers, gathers served from LDS, index/flag loads
// amortized across the 2 channels. grid (2048), block 256.
__global__ __launch_bounds__(256) void output_kernel(const float* __restrict__ G,
                                                     const float* __restrict__ Kn,
                                                     const float* __restrict__ flag,
                                                     const int* __restrict__ i01,
                                                     const float* __restrict__ wts,
                                                     float* __restrict__ out) {
    __shared__ float sG[2][N_TOT];
    __shared__ float sKn[2][N_TOT];
    __shared__ float swts[4];
    const int c0 = blockIdx.x * 2;
    const int t  = threadIdx.x;
    const int n4 = t * 4;

    if (t < 4) swts[t] = wts[t];

    #pragma unroll
    for (int ch = 0; ch < 2; ch++) {
        int c = c0 + ch;
        float4 gv = *(const float4*)&G[c * N_TOT + n4];
        float4 kv = *(const float4*)&Kn[c * N_TOT + n4];
        *(float4*)&sG[ch][n4]  = gv;
        *(float4*)&sKn[ch][n4] = kv;
        *(float4*)&out[c * N_TOT + n4] = gv;
        *(float4*)&out[C_DIM * N_TOT + c * N_TOT + n4] = kv;
    }

    float4 fv = *(const float4*)&flag[n4];
    const float fa[4] = {fv.x, fv.y, fv.z, fv.w};
    __syncthreads();

    const float w0 = swts[0], w1 = swts[1], w2 = swts[2], w3 = swts[3];

    float val[2][4];
    #pragma unroll
    for (int e = 0; e < 4; e++) {
        int n = n4 + e;
        float v0 = 0.0f, v1 = 0.0f;
        if (fa[e] == 1.0f) {
            int2 i0 = *(const int2*)&i01[n * 2];
            int2 i1 = *(const int2*)&i01[2 * N_TOT + n * 2];
            v0 = w0 * sKn[0][i0.x] + w1 * sKn[0][i0.y]
               + w2 * sG[0][i1.x]  + w3 * sG[0][i1.y];
            v1 = w0 * sKn[1][i0.x] + w1 * sKn[1][i0.y]
               + w2 * sG[1][i1.x]  + w3 * sG[1][i1.y];
        }
        if (n == 0) {
            bool m0 = (flag[0] == 1.0f);
            int2 i0 = *(const int2*)&i01[0];
            int2 i1 = *(const int2*)&i01[2 * N_TOT];
            if (!(m0 && i0.x == 0)) { v0 += w0 * sKn[0][0]; v1 += w0 * sKn[1][0]; }
            if (!(m0 && i0.y == 0)) { v0 += w1 * sKn[0][0]; v1 += w1 * sKn[1][0]; }
            if (!(m0 && i1.x == 0)) { v0 += w2 * sG[0][0];  v1 += w2 * sG[1][0]; }
            if (!(m0 && i1.y == 0)) { v0 += w3 * sG[0][0];  v1 += w3 * sG[1][0]; }
        }
        val[0][e] = v0; val[1][e] = v1;
    }
    #pragma unroll
    for (int ch = 0; ch < 2; ch++)
        *(float4*)&out[2 * C_DIM * N_TOT + (c0 + ch) * N_TOT + n4] =
            make_float4(val[ch][0], val[ch][1], val[ch][2], val[ch][3]);
}

// ---------------------------------------------------------------------------
extern "C" void kernel_launch(void* const* d_in, const int* in_sizes, int n_in,
                              void* d_out, int out_size, void* d_ws, size_t ws_size,
                              hipStream_t stream) {
    const float* G    = (const float*)d_in[0];
    const float* Kn   = (const float*)d_in[1];
    const float* flag = (const float*)d_in[2];
    float* out = (float*)d_out;

    // ws layout (~56.5 MB)
    char* p = (char*)d_ws;
    unsigned short* Phi = (unsigned short*)p;  p += (size_t)N_TOT * C_DIM * 2;  // 8 MB
    unsigned short* Khi = (unsigned short*)p;  p += (size_t)N_TOT * C_DIM * 2;  // 8 MB
    char* Plo = p;                             p += (size_t)N_TOT * C_DIM;      // 4 MB
    char* Klo = p;                             p += (size_t)N_TOT * C_DIM;      // 4 MB
    float* dotPart = (float*)p;                p += (size_t)8 * N_TOT * N_TOT * 4; // 32 MB
    float* normP   = (float*)p;                p += N_TOT * 4;
    float* normK   = (float*)p;                p += N_TOT * 4;
    float* wts     = (float*)p;                p += 16;
    float* w01     = (float*)p;                p += 4 * N_TOT * 4;
    int*   i01     = (int*)p;                  p += 4 * N_TOT * 4;
    int*   colidx  = (int*)p;                  p += N_TOT * 4;
    int*   n0p     = (int*)p;                  p += 16;
    int*   wl_hdr  = (int*)p;                  p += 2 * N_TOT * 4;
    int*   wl_cand = (int*)p;

    // zero only the atomically-accumulated norms (8 KB)
    hipMemsetAsync(normP, 0, 2 * N_TOT * sizeof(float), stream);

    split_norms<<<dim3(64, 16, 2), 256, 0, stream>>>(G, Kn, flag, Phi, Plo, Khi, Klo,
                                                     normP, normK, colidx, n0p);
    gemm_coarse<<<dim3(8, 8, 8), 256, 0, stream>>>(Phi, Khi, colidx, n0p, dotPart);
    select_k<<<1024, 256, 0, stream>>>(dotPart, normP, normK, colidx, n0p,
                                       w01, i01, wl_hdr, wl_cand);
    refine2<<<2048, 256, 0, stream>>>(Phi, Plo, Khi, Klo, normP, normK, colidx, n0p,
                                      wl_hdr, wl_cand, w01, i01);
    means_k<<<1, 256, 0, stream>>>(flag, w01, wts);
    output_kernel<<<2048, 256, 0, stream>>>(G, Kn, flag, i01, wts, out);
}

// Round 7
// 158.371 us; speedup vs baseline: 1.2312x; 1.0565x over previous
//
#include <hip/hip_runtime.h>
#include <hip/hip_bf16.h>
#include <math.h>

#define N_TOT 1024
#define C_DIM 4096
#define T_MARGIN 3e-4f   // coarse fp16 cosine err sigma ~6e-6; 3e-4 = ~50 sigma

typedef __attribute__((ext_vector_type(8))) _Float16 half8;
typedef __attribute__((ext_vector_type(8))) unsigned short ushort8;
typedef __attribute__((ext_vector_type(8))) char schar8;
typedef __attribute__((ext_vector_type(4))) float floatx4;

__device__ inline unsigned short f2h(float v) {
    _Float16 h = (_Float16)v;
    return __builtin_bit_cast(unsigned short, h);
}
__device__ inline float h2f(unsigned short u) {
    return (float)__builtin_bit_cast(_Float16, u);
}
// int8 residual with exponent borrowed from the fp16 hi part (err ~ulp/480).
__device__ inline char lo_enc(float v, unsigned short h) {
    int e = (h >> 10) & 31;
    float lo = v - h2f(h);
    float q = rintf(lo * 240.0f * __uint_as_float((unsigned)(152 - e) << 23));
    q = fmaxf(-127.0f, fminf(127.0f, q));
    return (char)(int)q;
}
__device__ inline float lo_dec(char q, unsigned short h) {
    int e = (h >> 10) & 31;
    return (float)q * __uint_as_float((unsigned)(e + 102) << 23) * (1.0f / 240.0f);
}

// lexicographic (value desc, index asc) insert into a sorted top-2 pair
__device__ inline void ins2(float v, int s, float& v1, int& s1, float& v2, int& s2) {
    if (v > v1 || (v == v1 && s < s1)) { v2 = v1; s2 = s1; v1 = v; s1 = s; }
    else if (v > v2 || (v == v2 && s < s2)) { v2 = v; s2 = s; }
}

// ---------------------------------------------------------------------------
// split+transpose+norms: X (C,N) fp32 -> Xhi[n][c] fp16, Xlo[n][c] int8;
// normX[n] += sum_c x^2 (atomic, pre-zeroed). float4 global loads; norms
// accumulated in the encode phase. Block (0,0,0) additionally computes the
// flag compaction (colidx: zeros then ones, n0 = #zeros). grid (64, 16, 2).
__global__ __launch_bounds__(256) void split_norms(const float* __restrict__ G,
                                                   const float* __restrict__ Kn,
                                                   const float* __restrict__ flag,
                                                   unsigned short* __restrict__ Phi,
                                                   char* __restrict__ Plo,
                                                   unsigned short* __restrict__ Khi,
                                                   char* __restrict__ Klo,
                                                   float* __restrict__ normP,
                                                   float* __restrict__ normK,
                                                   int* __restrict__ colidx,
                                                   int* __restrict__ n0p) {
    const int z = blockIdx.z;
    const float* X = z ? Kn : G;
    unsigned short* Xhi = z ? Khi : Phi;
    char* Xlo = z ? Klo : Plo;
    float* normX = z ? normK : normP;

    __shared__ float tile[64 * 65];
    const int t  = threadIdx.x;
    const int c0 = blockIdx.x * 64;
    const int n0 = blockIdx.y * 64;

    // load phase: float4 along n (4 loads/thread)
    #pragma unroll
    for (int s = 0; s < 4; s++) {
        int c_loc = s * 16 + (t >> 4);
        int n4    = (t & 15) * 4;
        float4 v = *(const float4*)&X[(size_t)(c0 + c_loc) * N_TOT + n0 + n4];
        tile[c_loc * 65 + n4 + 0] = v.x;
        tile[c_loc * 65 + n4 + 1] = v.y;
        tile[c_loc * 65 + n4 + 2] = v.z;
        tile[c_loc * 65 + n4 + 3] = v.w;
    }
    __syncthreads();

    // encode + per-column norms
    #pragma unroll
    for (int s = 0; s < 2; s++) {
        int n_loc = s * 32 + (t >> 3);
        int c8    = (t & 7) * 8;
        unsigned short h[8]; char l[8];
        float s2 = 0.0f;
        #pragma unroll
        for (int e = 0; e < 8; e++) {
            float v = tile[(c8 + e) * 65 + n_loc];
            s2 = fmaf(v, v, s2);
            h[e] = f2h(v);
            l[e] = lo_enc(v, h[e]);
        }
        s2 += __shfl_xor(s2, 1);
        s2 += __shfl_xor(s2, 2);
        s2 += __shfl_xor(s2, 4);
        if ((t & 7) == 0) atomicAdd(&normX[n0 + n_loc], s2);

        size_t base = (size_t)(n0 + n_loc) * C_DIM + c0 + c8;
        ushort8 hv; schar8 lv;
        #pragma unroll
        for (int e = 0; e < 8; e++) { hv[e] = h[e]; lv[e] = l[e]; }
        *(ushort8*)&Xhi[base] = hv;
        *(schar8*)&Xlo[base]  = lv;
    }

    // ---- embedded flag scan (block (0,0,0) only; block-uniform branch) ----
    if (blockIdx.x == 0 && blockIdx.y == 0 && blockIdx.z == 0) {
        __shared__ int cz[256];
        __shared__ int co[256];
        float4 fv = *(const float4*)&flag[4 * t];
        int f[4] = {fv.x == 0.0f, fv.y == 0.0f, fv.z == 0.0f, fv.w == 0.0f};
        int nz = f[0] + f[1] + f[2] + f[3];
        cz[t] = nz; co[t] = 4 - nz;
        __syncthreads();
        for (int off = 1; off < 256; off <<= 1) {
            int vz = (t >= off) ? cz[t - off] : 0;
            int vo = (t >= off) ? co[t - off] : 0;
            __syncthreads();
            cz[t] += vz; co[t] += vo;
            __syncthreads();
        }
        const int fn0 = cz[255];
        int zs = cz[t] - nz;
        int os = fn0 + co[t] - (4 - nz);
        #pragma unroll
        for (int e = 0; e < 4; e++) {
            int j = 4 * t + e;
            if (f[e]) colidx[zs++] = j;
            else      colidx[os++] = j;
        }
        if (t == 0) *n0p = fn0;
    }
}

// ---------------------------------------------------------------------------
// coarse fp16 MFMA GEMM. A-ROWS COMPACTED TO MASKED ROWS ONLY (flag==1, i.e.
// colidx[n0 + r]): unmasked rows never influence the output (means are
// masked, gather writes masked rows, and the row-0 artifact's index tests
// are all false when flag[0]==0). B = virtually-compacted slots as before.
// 128x128 tile, BK=64, K-split 8 -> grid (8,8,8); blocks with ib >= n1
// exit immediately (~half at random mask). PLAIN STORES to per-z planes.
__global__ __launch_bounds__(256, 2) void gemm_coarse(const unsigned short* __restrict__ Phi,
                                                      const unsigned short* __restrict__ Khi,
                                                      const int* __restrict__ colidx,
                                                      const int* __restrict__ n0p,
                                                      float* __restrict__ dotPart) {
    const int n0 = *n0p;
    const int n1 = N_TOT - n0;            // number of masked rows
    const int ib = blockIdx.x * 128;
    if (ib >= n1) return;                 // block-uniform early exit

    __shared__ unsigned short sA[128 * 64];   // 16 KB
    __shared__ unsigned short sB[128 * 64];   // 16 KB

    const int t    = threadIdx.x;
    const int wave = t >> 6, lane = t & 63;
    const int wm   = wave >> 1, wn = wave & 1;
    const int quad = lane >> 4, lrow = lane & 15;
    const int jb = blockIdx.y * 128;
    const int bz = blockIdx.z;
    const int k_beg = bz * 512;

    const int srow = t >> 3;                    // 0..31
    const int g    = (t & 7) ^ (srow & 7);      // q-invariant (32 % 8 == 0)

    // A: compacted masked row r = ib + q*32 + srow -> orig row colidx[n0+r]
    const unsigned short* gA[4];
    #pragma unroll
    for (int q = 0; q < 4; q++) {
        int r = ib + q * 32 + srow;
        int rr = (r < n1) ? r : (n1 - 1);       // clamp: duplicate last row
        int rowA = colidx[n0 + rr];
        gA[q] = Phi + (size_t)rowA * C_DIM + g * 8;
    }
    // B: compacted slots jb + q*32 + srow
    const unsigned short* gB[4];
    #pragma unroll
    for (int q = 0; q < 4; q++) {
        int s = jb + q * 32 + srow;
        int row = colidx[s];
        const unsigned short* src = (s < n0) ? Khi : Phi;
        gB[q] = src + (size_t)row * C_DIM + g * 8;
    }

    floatx4 acc[4][4] = {};

    for (int k0 = k_beg; k0 < k_beg + 512; k0 += 64) {
        #pragma unroll
        for (int q = 0; q < 4; q++)
            __builtin_amdgcn_global_load_lds(
                (const __attribute__((address_space(1))) void*)(gA[q] + k0),
                (__attribute__((address_space(3))) void*)((char*)sA + q * 4096 + t * 16), 16, 0, 0);
        #pragma unroll
        for (int q = 0; q < 4; q++)
            __builtin_amdgcn_global_load_lds(
                (const __attribute__((address_space(1))) void*)(gB[q] + k0),
                (__attribute__((address_space(3))) void*)((char*)sB + q * 4096 + t * 16), 16, 0, 0);
        __syncthreads();

        #pragma unroll
        for (int kk = 0; kk < 2; kk++) {
            const int gk = kk * 4 + quad;
            half8 a[4], b[4];
            #pragma unroll
            for (int ti = 0; ti < 4; ti++) {
                int m = wm * 64 + ti * 16 + lrow;
                a[ti] = *(const half8*)&sA[m * 64 + ((gk ^ (m & 7)) << 3)];
            }
            #pragma unroll
            for (int tj = 0; tj < 4; tj++) {
                int n = wn * 64 + tj * 16 + lrow;
                b[tj] = *(const half8*)&sB[n * 64 + ((gk ^ (n & 7)) << 3)];
            }
            #pragma unroll
            for (int ti = 0; ti < 4; ti++)
                #pragma unroll
                for (int tj = 0; tj < 4; tj++)
                    acc[ti][tj] = __builtin_amdgcn_mfma_f32_16x16x32_f16(a[ti], b[tj], acc[ti][tj], 0, 0, 0);
        }
        __syncthreads();
    }

    // plain stores into this z's plane at COMPACTED row index.
    float* outp = dotPart + ((size_t)bz << 20);
    #pragma unroll
    for (int tj = 0; tj < 4; tj++) {
        int j = jb + wn * 64 + tj * 16 + lrow;
        #pragma unroll
        for (int ti = 0; ti < 4; ti++) {
            #pragma unroll
            for (int reg = 0; reg < 4; reg++) {
                int i = ib + wm * 64 + ti * 16 + quad * 4 + reg;
                outp[i * N_TOT + j] = acc[ti][tj][reg];
            }
        }
    }
}

// ---------------------------------------------------------------------------
// select: one block per COMPACTED masked row r (orig row colidx[n0+r]).
// Blocks with r >= n1 zero their wl_hdr entries and exit (refine must not
// chase poisoned headers). Register-sum the 8 K-split planes, coarse
// cosines, single-pass top-2 per partition, threshold candidate ballot.
__global__ __launch_bounds__(256) void select_k(const float* __restrict__ dotPart,
                                                const float* __restrict__ normP,
                                                const float* __restrict__ normK,
                                                const int* __restrict__ colidx,
                                                const int* __restrict__ n0p,
                                                float* __restrict__ w01,   // [2][N][2]
                                                int* __restrict__ i01,     // [2][N][2]
                                                int* __restrict__ wl_hdr,  // [2N]
                                                int* __restrict__ wl_cand) { // [2N][16]
    __shared__ float sr_v1[2][4], sr_v2[2][4];
    __shared__ int   sr_s1[2][4], sr_s2[2][4];
    __shared__ int   s_cnt[2];
    __shared__ int   s_cand[2][16];

    const int r = blockIdx.x;
    const int t = threadIdx.x;
    const int n0 = *n0p;
    const int n1 = N_TOT - n0;
    if (r >= n1) {                       // unmasked-slot block: neutralize hdr
        if (t < 2) wl_hdr[2 * r + t] = 0;
        return;
    }
    const int row = colidx[n0 + r];      // original masked row
    const int wave = t >> 6, lane = t & 63;
    const float nr = normP[row];

    if (t < 2) s_cnt[t] = 0;

    // 8-plane register sum (compacted row r)
    const float* base = dotPart + (size_t)r * N_TOT + 4 * t;
    float4 p0 = *(const float4*)(base);
    float4 p1 = *(const float4*)(base + (1ull << 20));
    float4 p2 = *(const float4*)(base + (2ull << 20));
    float4 p3 = *(const float4*)(base + (3ull << 20));
    float4 p4 = *(const float4*)(base + (4ull << 20));
    float4 p5 = *(const float4*)(base + (5ull << 20));
    float4 p6 = *(const float4*)(base + (6ull << 20));
    float4 p7 = *(const float4*)(base + (7ull << 20));
    float4 dv;
    dv.x = ((p0.x + p1.x) + (p2.x + p3.x)) + ((p4.x + p5.x) + (p6.x + p7.x));
    dv.y = ((p0.y + p1.y) + (p2.y + p3.y)) + ((p4.y + p5.y) + (p6.y + p7.y));
    dv.z = ((p0.z + p1.z) + (p2.z + p3.z)) + ((p4.z + p5.z) + (p6.z + p7.z));
    dv.w = ((p0.w + p1.w) + (p2.w + p3.w)) + ((p4.w + p5.w) + (p6.w + p7.w));

    // coarse cosines for my 4 compacted B-slots
    float cv[4];
    #pragma unroll
    for (int e = 0; e < 4; e++) {
        int s = 4 * t + e;
        int gj = colidx[s];
        float nb = (s < n0) ? normK[gj] : normP[gj];
        float d  = (e == 0) ? dv.x : (e == 1) ? dv.y : (e == 2) ? dv.z : dv.w;
        cv[e] = d * rsqrtf(nr * nb);
    }

    // single-pass wave-local top-2 per partition (no barriers inside)
    #pragma unroll
    for (int zz = 0; zz < 2; zz++) {
        float v1 = -INFINITY, v2 = -INFINITY;
        int   s1 = 0x7FFFFFFF, s2 = 0x7FFFFFFF;
        #pragma unroll
        for (int e = 0; e < 4; e++) {
            int s = 4 * t + e;
            bool inz = zz ? (s >= n0) : (s < n0);
            if (inz) ins2(cv[e], s, v1, s1, v2, s2);
        }
        #pragma unroll
        for (int off = 32; off > 0; off >>= 1) {
            float o1 = __shfl_xor(v1, off); int q1 = __shfl_xor(s1, off);
            float o2 = __shfl_xor(v2, off); int q2 = __shfl_xor(s2, off);
            ins2(o1, q1, v1, s1, v2, s2);
            ins2(o2, q2, v1, s1, v2, s2);
        }
        if (lane == 0) {
            sr_v1[zz][wave] = v1; sr_s1[zz][wave] = s1;
            sr_v2[zz][wave] = v2; sr_s2[zz][wave] = s2;
        }
    }
    __syncthreads();

    // cross-wave merge (uniform in all threads) + threshold candidate ballot
    float m1z[2], m2z[2]; int b1z[2], b2z[2];
    #pragma unroll
    for (int zz = 0; zz < 2; zz++) {
        float m1 = -INFINITY, m2 = -INFINITY;
        int   b1 = 0x7FFFFFFF, b2 = 0x7FFFFFFF;
        #pragma unroll
        for (int w = 0; w < 4; w++) {
            ins2(sr_v1[zz][w], sr_s1[zz][w], m1, b1, m2, b2);
            ins2(sr_v2[zz][w], sr_s2[zz][w], m1, b1, m2, b2);
        }
        m1z[zz] = m1; m2z[zz] = m2; b1z[zz] = b1; b2z[zz] = b2;
        const float thr = m2 - T_MARGIN;
        #pragma unroll
        for (int e = 0; e < 4; e++) {
            int s = 4 * t + e;
            bool inz = zz ? (s >= n0) : (s < n0);
            if (inz && cv[e] > thr) {
                int idx = atomicAdd(&s_cnt[zz], 1);   // shared-mem atomic only
                if (idx < 16) s_cand[zz][idx] = s;    // >16 cands: graceful cap
            }
        }
    }
    __syncthreads();

    bool need[2]; int cntz[2];
    #pragma unroll
    for (int zz = 0; zz < 2; zz++) {
        const int cnt = min(s_cnt[zz], 16);
        cntz[zz] = cnt;
        const bool trusted = (s_cnt[zz] == 2) && (m1z[zz] - m2z[zz] > T_MARGIN);
        need[zz] = !trusted;
        if (t == 0) {
            wl_hdr[2 * r + zz] = trusted ? 0 : cnt;
            if (trusted) {
                int base2 = (zz * N_TOT + row) * 2;
                w01[base2]     = m1z[zz];
                w01[base2 + 1] = m2z[zz];
                i01[base2]     = colidx[b1z[zz]];
                i01[base2 + 1] = colidx[b2z[zz]];
            }
        }
    }
    __syncthreads();

    #pragma unroll
    for (int zz = 0; zz < 2; zz++)
        if (need[zz] && t < cntz[zz])
            wl_cand[(2 * r + zz) * 16 + t] = s_cand[zz][t];
}

// ---------------------------------------------------------------------------
// refine2: grid 2048, block = (r,zz) item over COMPACTED rows; instant exit
// when hdr==0 (covers r >= n1). Reconstruct the exact A row in LDS, 8
// parallel 32-lane candidate dots, exact top-2 with global-index tie-break.
__global__ __launch_bounds__(256) void refine2(const unsigned short* __restrict__ Phi,
                                               const char* __restrict__ Plo,
                                               const unsigned short* __restrict__ Khi,
                                               const char* __restrict__ Klo,
                                               const float* __restrict__ normP,
                                               const float* __restrict__ normK,
                                               const int* __restrict__ colidx,
                                               const int* __restrict__ n0p,
                                               const int* __restrict__ wl_hdr,
                                               const int* __restrict__ wl_cand,
                                               float* __restrict__ w01,
                                               int* __restrict__ i01) {
    __shared__ float sAf[C_DIM];     // 16 KB exact A row
    __shared__ float s_rcv[16];
    __shared__ int   s_rcj[16];

    const int item = blockIdx.x;
    const int cnt  = wl_hdr[item];
    if (cnt == 0) return;            // trusted or out-of-range -> nothing

    const int n0 = *n0p;
    const int r  = item >> 1;
    const int zz = item & 1;
    const int row = colidx[n0 + r];  // original masked row
    const int t   = threadIdx.x;
    const int grp = t >> 5, l32 = t & 31;
    const float nr = normP[row];

    // reconstruct exact A row
    {
        const unsigned short* Ah = Phi + (size_t)row * C_DIM;
        const char*           Al = Plo + (size_t)row * C_DIM;
        #pragma unroll
        for (int s = 0; s < 2; s++) {
            int c = t * 16 + s * 8;
            ushort8 hb = *(const ushort8*)&Ah[c];
            schar8  lb = *(const schar8*)&Al[c];
            #pragma unroll
            for (int e = 0; e < 8; e++) sAf[c + e] = h2f(hb[e]) + lo_dec(lb[e], hb[e]);
        }
    }
    __syncthreads();

    #pragma unroll
    for (int p = 0; p < 2; p++) {
        if (p == 1 && cnt <= 8) break;          // uniform
        const int q = grp + 8 * p;
        float acc = 0.0f;
        int gj = 0; float nb = 1.0f;
        if (q < cnt) {
            const int cs = wl_cand[item * 16 + q];
            gj = colidx[cs];
            nb = (cs < n0) ? normK[gj] : normP[gj];
            const unsigned short* bh_row = ((cs < n0) ? Khi : Phi) + (size_t)gj * C_DIM;
            const char*           bl_row = ((cs < n0) ? Klo : Plo) + (size_t)gj * C_DIM;
            #pragma unroll 4
            for (int it = 0; it < 16; it++) {
                int c = it * 256 + l32 * 8;
                ushort8 hb = *(const ushort8*)&bh_row[c];
                schar8  lb = *(const schar8*)&bl_row[c];
                #pragma unroll
                for (int e = 0; e < 8; e++)
                    acc = fmaf(sAf[c + e], h2f(hb[e]) + lo_dec(lb[e], hb[e]), acc);
            }
        }
        #pragma unroll
        for (int off = 16; off > 0; off >>= 1) acc += __shfl_xor(acc, off);
        if (l32 == 0 && q < cnt) {
            s_rcv[q] = acc * rsqrtf(nr * nb);
            s_rcj[q] = gj;
        }
    }
    __syncthreads();

    if (t == 0) {
        float v1 = -INFINITY, v2 = -INFINITY;
        int   j1 = 0x7FFFFFFF, j2 = 0x7FFFFFFF;
        for (int q = 0; q < cnt; q++) {
            float cvx = s_rcv[q];
            int   j   = s_rcj[q];
            if (cvx > v1 || (cvx == v1 && j < j1)) {
                v2 = v1; j2 = j1; v1 = cvx; j1 = j;
            } else if (cvx > v2 || (cvx == v2 && j < j2)) {
                v2 = cvx; j2 = j;
            }
        }
        if (j1 == 0x7FFFFFFF) j1 = 0;   // degenerate-partition guard
        if (j2 == 0x7FFFFFFF) j2 = j1;
        int base = (zz * N_TOT + row) * 2;
        w01[base]     = v1;
        w01[base + 1] = v2;
        i01[base]     = j1;
        i01[base + 1] = j2;
    }
}

// ---------------------------------------------------------------------------
// means_k: single block. Masked means of the 4 weight series over w01,
// softmax, write wts[4]. READS GUARDED by m==1: unmasked w01 entries are
// uninitialized (ws poison) and 0*NaN would corrupt the sum.
__global__ __launch_bounds__(256) void means_k(const float* __restrict__ flag,
                                               const float* __restrict__ w01,
                                               float* __restrict__ wts) {
    __shared__ float red[5][4];
    const int t = threadIdx.x;
    const int wave = t >> 6, lane = t & 63;

    float pm[5] = {};
    #pragma unroll
    for (int e = 0; e < 4; e++) {
        int n = 4 * t + e;
        if (flag[n] == 1.0f) {
            pm[0] += 1.0f;
            pm[1] += w01[n * 2 + 0];
            pm[2] += w01[n * 2 + 1];
            pm[3] += w01[2 * N_TOT + n * 2 + 0];
            pm[4] += w01[2 * N_TOT + n * 2 + 1];
        }
    }
    #pragma unroll
    for (int i = 0; i < 5; i++)
        #pragma unroll
        for (int off = 32; off > 0; off >>= 1)
            pm[i] += __shfl_xor(pm[i], off);
    if (lane == 0) {
        #pragma unroll
        for (int i = 0; i < 5; i++) red[i][wave] = pm[i];
    }
    __syncthreads();
    if (t == 0) {
        float tot[5];
        #pragma unroll
        for (int i = 0; i < 5; i++)
            tot[i] = red[i][0] + red[i][1] + red[i][2] + red[i][3];
        float inv = 1.0f / tot[0];
        float mv[4] = {tot[1] * inv, tot[2] * inv, tot[3] * inv, tot[4] * inv};
        float mx = fmaxf(fmaxf(mv[0], mv[1]), fmaxf(mv[2], mv[3]));
        float e[4], s = 0.0f;
        #pragma unroll
        for (int q = 0; q < 4; q++) { e[q] = expf(mv[q] - mx); s += e[q]; }
        #pragma unroll
        for (int q = 0; q < 4; q++) wts[q] = e[q] / s;
    }
}

// ---------------------------------------------------------------------------
// output: TWO channels per block. Stage both G/Kn rows in LDS (coalesced),
// copies from staged registers, gathers served from LDS, index/flag loads
// amortized across the 2 channels. grid (2048), block 256.
// NOTE: i01 for unmasked n is uninitialized, but it is only read under
// fa[e]==1 or inside (m0 && ...) predicates that are false when flag[0]==0.
__global__ __launch_bounds__(256) void output_kernel(const float* __restrict__ G,
                                                     const float* __restrict__ Kn,
                                                     const float* __restrict__ flag,
                                                     const int* __restrict__ i01,
                                                     const float* __restrict__ wts,
                                                     float* __restrict__ out) {
    __shared__ float sG[2][N_TOT];
    __shared__ float sKn[2][N_TOT];
    __shared__ float swts[4];
    const int c0 = blockIdx.x * 2;
    const int t  = threadIdx.x;
    const int n4 = t * 4;

    if (t < 4) swts[t] = wts[t];

    #pragma unroll
    for (int ch = 0; ch < 2; ch++) {
        int c = c0 + ch;
        float4 gv = *(const float4*)&G[c * N_TOT + n4];
        float4 kv = *(const float4*)&Kn[c * N_TOT + n4];
        *(float4*)&sG[ch][n4]  = gv;
        *(float4*)&sKn[ch][n4] = kv;
        *(float4*)&out[c * N_TOT + n4] = gv;
        *(float4*)&out[C_DIM * N_TOT + c * N_TOT + n4] = kv;
    }

    float4 fv = *(const float4*)&flag[n4];
    const float fa[4] = {fv.x, fv.y, fv.z, fv.w};
    __syncthreads();

    const float w0 = swts[0], w1 = swts[1], w2 = swts[2], w3 = swts[3];

    float val[2][4];
    #pragma unroll
    for (int e = 0; e < 4; e++) {
        int n = n4 + e;
        float v0 = 0.0f, v1 = 0.0f;
        if (fa[e] == 1.0f) {
            int2 i0 = *(const int2*)&i01[n * 2];
            int2 i1 = *(const int2*)&i01[2 * N_TOT + n * 2];
            v0 = w0 * sKn[0][i0.x] + w1 * sKn[0][i0.y]
               + w2 * sG[0][i1.x]  + w3 * sG[0][i1.y];
            v1 = w0 * sKn[1][i0.x] + w1 * sKn[1][i0.y]
               + w2 * sG[1][i1.x]  + w3 * sG[1][i1.y];
        }
        if (n == 0) {
            bool m0 = (flag[0] == 1.0f);
            // when m0 is false these indices are never compared-true, and
            // they may be uninitialized — guard the loads themselves.
            int2 i0 = m0 ? *(const int2*)&i01[0]        : make_int2(-1, -1);
            int2 i1 = m0 ? *(const int2*)&i01[2 * N_TOT] : make_int2(-1, -1);
            if (!(m0 && i0.x == 0)) { v0 += w0 * sKn[0][0]; v1 += w0 * sKn[1][0]; }
            if (!(m0 && i0.y == 0)) { v0 += w1 * sKn[0][0]; v1 += w1 * sKn[1][0]; }
            if (!(m0 && i1.x == 0)) { v0 += w2 * sG[0][0];  v1 += w2 * sG[1][0]; }
            if (!(m0 && i1.y == 0)) { v0 += w3 * sG[0][0];  v1 += w3 * sG[1][0]; }
        }
        val[0][e] = v0; val[1][e] = v1;
    }
    #pragma unroll
    for (int ch = 0; ch < 2; ch++)
        *(float4*)&out[2 * C_DIM * N_TOT + (c0 + ch) * N_TOT + n4] =
            make_float4(val[ch][0], val[ch][1], val[ch][2], val[ch][3]);
}

// ---------------------------------------------------------------------------
extern "C" void kernel_launch(void* const* d_in, const int* in_sizes, int n_in,
                              void* d_out, int out_size, void* d_ws, size_t ws_size,
                              hipStream_t stream) {
    const float* G    = (const float*)d_in[0];
    const float* Kn   = (const float*)d_in[1];
    const float* flag = (const float*)d_in[2];
    float* out = (float*)d_out;

    // ws layout (~56.5 MB)
    char* p = (char*)d_ws;
    unsigned short* Phi = (unsigned short*)p;  p += (size_t)N_TOT * C_DIM * 2;  // 8 MB
    unsigned short* Khi = (unsigned short*)p;  p += (size_t)N_TOT * C_DIM * 2;  // 8 MB
    char* Plo = p;                             p += (size_t)N_TOT * C_DIM;      // 4 MB
    char* Klo = p;                             p += (size_t)N_TOT * C_DIM;      // 4 MB
    float* dotPart = (float*)p;                p += (size_t)8 * N_TOT * N_TOT * 4; // 32 MB
    float* normP   = (float*)p;                p += N_TOT * 4;
    float* normK   = (float*)p;                p += N_TOT * 4;
    float* wts     = (float*)p;                p += 16;
    float* w01     = (float*)p;                p += 4 * N_TOT * 4;
    int*   i01     = (int*)p;                  p += 4 * N_TOT * 4;
    int*   colidx  = (int*)p;                  p += N_TOT * 4;
    int*   n0p     = (int*)p;                  p += 16;
    int*   wl_hdr  = (int*)p;                  p += 2 * N_TOT * 4;
    int*   wl_cand = (int*)p;

    // zero only the atomically-accumulated norms (8 KB)
    hipMemsetAsync(normP, 0, 2 * N_TOT * sizeof(float), stream);

    split_norms<<<dim3(64, 16, 2), 256, 0, stream>>>(G, Kn, flag, Phi, Plo, Khi, Klo,
                                                     normP, normK, colidx, n0p);
    gemm_coarse<<<dim3(8, 8, 8), 256, 0, stream>>>(Phi, Khi, colidx, n0p, dotPart);
    select_k<<<1024, 256, 0, stream>>>(dotPart, normP, normK, colidx, n0p,
                                       w01, i01, wl_hdr, wl_cand);
    refine2<<<2048, 256, 0, stream>>>(Phi, Plo, Khi, Klo, normP, normK, colidx, n0p,
                                      wl_hdr, wl_cand, w01, i01);
    means_k<<<1, 256, 0, stream>>>(flag, w01, wts);
    output_kernel<<<2048, 256, 0, stream>>>(G, Kn, flag, i01, wts, out);
}

// Round 8
// 155.591 us; speedup vs baseline: 1.2532x; 1.0179x over previous
//
#include <hip/hip_runtime.h>
#include <hip/hip_bf16.h>
#include <math.h>

#define N_TOT 1024
#define C_DIM 4096
#define T_MARGIN 3e-4f   // coarse fp16 cosine err sigma ~6e-6; 3e-4 = ~50 sigma

typedef __attribute__((ext_vector_type(8))) _Float16 half8;
typedef __attribute__((ext_vector_type(8))) unsigned short ushort8;
typedef __attribute__((ext_vector_type(8))) char schar8;
typedef __attribute__((ext_vector_type(4))) float floatx4;

__device__ inline unsigned short f2h(float v) {
    _Float16 h = (_Float16)v;
    return __builtin_bit_cast(unsigned short, h);
}
__device__ inline float h2f(unsigned short u) {
    return (float)__builtin_bit_cast(_Float16, u);
}
// int8 residual with exponent borrowed from the fp16 hi part (err ~ulp/480).
__device__ inline char lo_enc(float v, unsigned short h) {
    int e = (h >> 10) & 31;
    float lo = v - h2f(h);
    float q = rintf(lo * 240.0f * __uint_as_float((unsigned)(152 - e) << 23));
    q = fmaxf(-127.0f, fminf(127.0f, q));
    return (char)(int)q;
}
__device__ inline float lo_dec(char q, unsigned short h) {
    int e = (h >> 10) & 31;
    return (float)q * __uint_as_float((unsigned)(e + 102) << 23) * (1.0f / 240.0f);
}

// lexicographic (value desc, index asc) insert into a sorted top-2 pair
__device__ inline void ins2(float v, int s, float& v1, int& s1, float& v2, int& s2) {
    if (v > v1 || (v == v1 && s < s1)) { v2 = v1; s2 = s1; v1 = v; s1 = s; }
    else if (v > v2 || (v == v2 && s < s2)) { v2 = v; s2 = s; }
}

// ---------------------------------------------------------------------------
// split+transpose+norms. SPARSE ENCODE: P (generated) columns are only ever
// read for flag==1 rows; K (known) columns only for flag==0 rows — skip the
// encode/store/norm for the other half (their Xhi/Xlo/norm are never read).
// grid (64, 16, 2).
__global__ __launch_bounds__(256) void split_norms(const float* __restrict__ G,
                                                   const float* __restrict__ Kn,
                                                   const float* __restrict__ flag,
                                                   unsigned short* __restrict__ Phi,
                                                   char* __restrict__ Plo,
                                                   unsigned short* __restrict__ Khi,
                                                   char* __restrict__ Klo,
                                                   float* __restrict__ normP,
                                                   float* __restrict__ normK,
                                                   int* __restrict__ colidx,
                                                   int* __restrict__ n0p) {
    const int z = blockIdx.z;
    const float* X = z ? Kn : G;
    unsigned short* Xhi = z ? Khi : Phi;
    char* Xlo = z ? Klo : Plo;
    float* normX = z ? normK : normP;

    __shared__ float tile[64 * 65];
    const int t  = threadIdx.x;
    const int c0 = blockIdx.x * 64;
    const int n0 = blockIdx.y * 64;

    // load phase: float4 along n (4 loads/thread)
    #pragma unroll
    for (int s = 0; s < 4; s++) {
        int c_loc = s * 16 + (t >> 4);
        int n4    = (t & 15) * 4;
        float4 v = *(const float4*)&X[(size_t)(c0 + c_loc) * N_TOT + n0 + n4];
        tile[c_loc * 65 + n4 + 0] = v.x;
        tile[c_loc * 65 + n4 + 1] = v.y;
        tile[c_loc * 65 + n4 + 2] = v.z;
        tile[c_loc * 65 + n4 + 3] = v.w;
    }
    __syncthreads();

    // encode + per-column norms, only for needed columns:
    //   z==0 (P): flag==1 columns;  z==1 (K): flag==0 columns.
    #pragma unroll
    for (int s = 0; s < 2; s++) {
        int n_loc = s * 32 + (t >> 3);
        float fl = flag[n0 + n_loc];
        bool need = z ? (fl == 0.0f) : (fl == 1.0f);
        if (need) {
            int c8 = (t & 7) * 8;
            unsigned short h[8]; char l[8];
            float s2 = 0.0f;
            #pragma unroll
            for (int e = 0; e < 8; e++) {
                float v = tile[(c8 + e) * 65 + n_loc];
                s2 = fmaf(v, v, s2);
                h[e] = f2h(v);
                l[e] = lo_enc(v, h[e]);
            }
            s2 += __shfl_xor(s2, 1);
            s2 += __shfl_xor(s2, 2);
            s2 += __shfl_xor(s2, 4);
            if ((t & 7) == 0) atomicAdd(&normX[n0 + n_loc], s2);

            size_t base = (size_t)(n0 + n_loc) * C_DIM + c0 + c8;
            ushort8 hv; schar8 lv;
            #pragma unroll
            for (int e = 0; e < 8; e++) { hv[e] = h[e]; lv[e] = l[e]; }
            *(ushort8*)&Xhi[base] = hv;
            *(schar8*)&Xlo[base]  = lv;
        }
    }

    // ---- embedded flag scan (block (0,0,0) only; block-uniform branch) ----
    if (blockIdx.x == 0 && blockIdx.y == 0 && blockIdx.z == 0) {
        __shared__ int cz[256];
        __shared__ int co[256];
        float4 fv = *(const float4*)&flag[4 * t];
        int f[4] = {fv.x == 0.0f, fv.y == 0.0f, fv.z == 0.0f, fv.w == 0.0f};
        int nz = f[0] + f[1] + f[2] + f[3];
        cz[t] = nz; co[t] = 4 - nz;
        __syncthreads();
        for (int off = 1; off < 256; off <<= 1) {
            int vz = (t >= off) ? cz[t - off] : 0;
            int vo = (t >= off) ? co[t - off] : 0;
            __syncthreads();
            cz[t] += vz; co[t] += vo;
            __syncthreads();
        }
        const int fn0 = cz[255];
        int zs = cz[t] - nz;
        int os = fn0 + co[t] - (4 - nz);
        #pragma unroll
        for (int e = 0; e < 4; e++) {
            int j = 4 * t + e;
            if (f[e]) colidx[zs++] = j;
            else      colidx[os++] = j;
        }
        if (t == 0) *n0p = fn0;
    }
}

// ---------------------------------------------------------------------------
// coarse fp16 MFMA GEMM, A-rows = compacted masked rows (colidx[n0+r]).
// 64x128 tile, BK=64, K-split 8 -> grid (16,8,8); blocks with ib >= n1 exit.
// 24 KB LDS, 4 blocks/CU budget -> better staging-latency hiding than 128^2.
__global__ __launch_bounds__(256, 4) void gemm_coarse(const unsigned short* __restrict__ Phi,
                                                      const unsigned short* __restrict__ Khi,
                                                      const int* __restrict__ colidx,
                                                      const int* __restrict__ n0p,
                                                      float* __restrict__ dotPart) {
    const int n0 = *n0p;
    const int n1 = N_TOT - n0;            // number of masked rows
    const int ib = blockIdx.x * 64;
    if (ib >= n1) return;                 // block-uniform early exit

    __shared__ unsigned short sA[64 * 64];    // 8 KB
    __shared__ unsigned short sB[128 * 64];   // 16 KB

    const int t    = threadIdx.x;
    const int wave = t >> 6, lane = t & 63;
    const int wm   = wave >> 1, wn = wave & 1;
    const int quad = lane >> 4, lrow = lane & 15;
    const int jb = blockIdx.y * 128;
    const int bz = blockIdx.z;
    const int k_beg = bz * 512;

    const int srow = t >> 3;                    // 0..31
    const int g    = (t & 7) ^ (srow & 7);      // q-invariant (32 % 8 == 0)

    // A: compacted masked row r = ib + q*32 + srow -> orig row colidx[n0+r]
    const unsigned short* gA[2];
    #pragma unroll
    for (int q = 0; q < 2; q++) {
        int r = ib + q * 32 + srow;
        int rr = (r < n1) ? r : (n1 - 1);       // clamp: duplicate last row
        gA[q] = Phi + (size_t)colidx[n0 + rr] * C_DIM + g * 8;
    }
    // B: compacted slots jb + q*32 + srow
    const unsigned short* gB[4];
    #pragma unroll
    for (int q = 0; q < 4; q++) {
        int s = jb + q * 32 + srow;
        int row = colidx[s];
        const unsigned short* src = (s < n0) ? Khi : Phi;
        gB[q] = src + (size_t)row * C_DIM + g * 8;
    }

    floatx4 acc[2][4] = {};

    for (int k0 = k_beg; k0 < k_beg + 512; k0 += 64) {
        #pragma unroll
        for (int q = 0; q < 2; q++)
            __builtin_amdgcn_global_load_lds(
                (const __attribute__((address_space(1))) void*)(gA[q] + k0),
                (__attribute__((address_space(3))) void*)((char*)sA + q * 4096 + t * 16), 16, 0, 0);
        #pragma unroll
        for (int q = 0; q < 4; q++)
            __builtin_amdgcn_global_load_lds(
                (const __attribute__((address_space(1))) void*)(gB[q] + k0),
                (__attribute__((address_space(3))) void*)((char*)sB + q * 4096 + t * 16), 16, 0, 0);
        __syncthreads();

        #pragma unroll
        for (int kk = 0; kk < 2; kk++) {
            const int gk = kk * 4 + quad;
            half8 a[2], b[4];
            #pragma unroll
            for (int ti = 0; ti < 2; ti++) {
                int m = wm * 32 + ti * 16 + lrow;
                a[ti] = *(const half8*)&sA[m * 64 + ((gk ^ (m & 7)) << 3)];
            }
            #pragma unroll
            for (int tj = 0; tj < 4; tj++) {
                int n = wn * 64 + tj * 16 + lrow;
                b[tj] = *(const half8*)&sB[n * 64 + ((gk ^ (n & 7)) << 3)];
            }
            #pragma unroll
            for (int ti = 0; ti < 2; ti++)
                #pragma unroll
                for (int tj = 0; tj < 4; tj++)
                    acc[ti][tj] = __builtin_amdgcn_mfma_f32_16x16x32_f16(a[ti], b[tj], acc[ti][tj], 0, 0, 0);
        }
        __syncthreads();
    }

    // plain stores into this z's plane at COMPACTED row index.
    float* outp = dotPart + ((size_t)bz << 20);
    #pragma unroll
    for (int tj = 0; tj < 4; tj++) {
        int j = jb + wn * 64 + tj * 16 + lrow;
        #pragma unroll
        for (int ti = 0; ti < 2; ti++) {
            #pragma unroll
            for (int reg = 0; reg < 4; reg++) {
                int i = ib + wm * 32 + ti * 16 + quad * 4 + reg;
                outp[i * N_TOT + j] = acc[ti][tj][reg];
            }
        }
    }
}

// ---------------------------------------------------------------------------
// select: one block per COMPACTED masked row r (orig row colidx[n0+r]).
// Blocks with r >= n1 zero their wl_hdr entries and exit. Register-sum the
// 8 K-split planes, coarse cosines, single-pass top-2 per partition,
// threshold candidate ballot. Trusted: write w01/i01, hdr=0. Untrusted:
// hdr=cnt + candidate list.
__global__ __launch_bounds__(256) void select_k(const float* __restrict__ dotPart,
                                                const float* __restrict__ normP,
                                                const float* __restrict__ normK,
                                                const int* __restrict__ colidx,
                                                const int* __restrict__ n0p,
                                                float* __restrict__ w01,   // [2][N][2]
                                                int* __restrict__ i01,     // [2][N][2]
                                                int* __restrict__ wl_hdr,  // [2N]
                                                int* __restrict__ wl_cand) { // [2N][16]
    __shared__ float sr_v1[2][4], sr_v2[2][4];
    __shared__ int   sr_s1[2][4], sr_s2[2][4];
    __shared__ int   s_cnt[2];
    __shared__ int   s_cand[2][16];

    const int r = blockIdx.x;
    const int t = threadIdx.x;
    const int n0 = *n0p;
    const int n1 = N_TOT - n0;
    if (r >= n1) {                       // unmasked-slot block: neutralize hdr
        if (t < 2) wl_hdr[2 * r + t] = 0;
        return;
    }
    const int row = colidx[n0 + r];      // original masked row
    const int wave = t >> 6, lane = t & 63;
    const float nr = normP[row];

    if (t < 2) s_cnt[t] = 0;

    // 8-plane register sum (compacted row r)
    const float* base = dotPart + (size_t)r * N_TOT + 4 * t;
    float4 p0 = *(const float4*)(base);
    float4 p1 = *(const float4*)(base + (1ull << 20));
    float4 p2 = *(const float4*)(base + (2ull << 20));
    float4 p3 = *(const float4*)(base + (3ull << 20));
    float4 p4 = *(const float4*)(base + (4ull << 20));
    float4 p5 = *(const float4*)(base + (5ull << 20));
    float4 p6 = *(const float4*)(base + (6ull << 20));
    float4 p7 = *(const float4*)(base + (7ull << 20));
    float4 dv;
    dv.x = ((p0.x + p1.x) + (p2.x + p3.x)) + ((p4.x + p5.x) + (p6.x + p7.x));
    dv.y = ((p0.y + p1.y) + (p2.y + p3.y)) + ((p4.y + p5.y) + (p6.y + p7.y));
    dv.z = ((p0.z + p1.z) + (p2.z + p3.z)) + ((p4.z + p5.z) + (p6.z + p7.z));
    dv.w = ((p0.w + p1.w) + (p2.w + p3.w)) + ((p4.w + p5.w) + (p6.w + p7.w));

    // coarse cosines for my 4 compacted B-slots
    float cv[4];
    #pragma unroll
    for (int e = 0; e < 4; e++) {
        int s = 4 * t + e;
        int gj = colidx[s];
        float nb = (s < n0) ? normK[gj] : normP[gj];
        float d  = (e == 0) ? dv.x : (e == 1) ? dv.y : (e == 2) ? dv.z : dv.w;
        cv[e] = d * rsqrtf(nr * nb);
    }

    // single-pass wave-local top-2 per partition (no barriers inside)
    #pragma unroll
    for (int zz = 0; zz < 2; zz++) {
        float v1 = -INFINITY, v2 = -INFINITY;
        int   s1 = 0x7FFFFFFF, s2 = 0x7FFFFFFF;
        #pragma unroll
        for (int e = 0; e < 4; e++) {
            int s = 4 * t + e;
            bool inz = zz ? (s >= n0) : (s < n0);
            if (inz) ins2(cv[e], s, v1, s1, v2, s2);
        }
        #pragma unroll
        for (int off = 32; off > 0; off >>= 1) {
            float o1 = __shfl_xor(v1, off); int q1 = __shfl_xor(s1, off);
            float o2 = __shfl_xor(v2, off); int q2 = __shfl_xor(s2, off);
            ins2(o1, q1, v1, s1, v2, s2);
            ins2(o2, q2, v1, s1, v2, s2);
        }
        if (lane == 0) {
            sr_v1[zz][wave] = v1; sr_s1[zz][wave] = s1;
            sr_v2[zz][wave] = v2; sr_s2[zz][wave] = s2;
        }
    }
    __syncthreads();

    // cross-wave merge (uniform in all threads) + threshold candidate ballot
    float m1z[2], m2z[2]; int b1z[2], b2z[2];
    #pragma unroll
    for (int zz = 0; zz < 2; zz++) {
        float m1 = -INFINITY, m2 = -INFINITY;
        int   b1 = 0x7FFFFFFF, b2 = 0x7FFFFFFF;
        #pragma unroll
        for (int w = 0; w < 4; w++) {
            ins2(sr_v1[zz][w], sr_s1[zz][w], m1, b1, m2, b2);
            ins2(sr_v2[zz][w], sr_s2[zz][w], m1, b1, m2, b2);
        }
        m1z[zz] = m1; m2z[zz] = m2; b1z[zz] = b1; b2z[zz] = b2;
        const float thr = m2 - T_MARGIN;
        #pragma unroll
        for (int e = 0; e < 4; e++) {
            int s = 4 * t + e;
            bool inz = zz ? (s >= n0) : (s < n0);
            if (inz && cv[e] > thr) {
                int idx = atomicAdd(&s_cnt[zz], 1);   // shared-mem atomic only
                if (idx < 16) s_cand[zz][idx] = s;    // >16 cands: graceful cap
            }
        }
    }
    __syncthreads();

    bool need[2]; int cntz[2];
    #pragma unroll
    for (int zz = 0; zz < 2; zz++) {
        const int cnt = min(s_cnt[zz], 16);
        cntz[zz] = cnt;
        const bool trusted = (s_cnt[zz] == 2) && (m1z[zz] - m2z[zz] > T_MARGIN);
        need[zz] = !trusted;
        if (t == 0) {
            wl_hdr[2 * r + zz] = trusted ? 0 : cnt;
            if (trusted) {
                int base2 = (zz * N_TOT + row) * 2;
                w01[base2]     = m1z[zz];
                w01[base2 + 1] = m2z[zz];
                i01[base2]     = colidx[b1z[zz]];
                i01[base2 + 1] = colidx[b2z[zz]];
            }
        }
    }
    __syncthreads();

    #pragma unroll
    for (int zz = 0; zz < 2; zz++)
        if (need[zz] && t < cntz[zz])
            wl_cand[(2 * r + zz) * 16 + t] = s_cand[zz][t];
}

// ---------------------------------------------------------------------------
// refine2: grid 2048, block = (r,zz) item over COMPACTED rows; instant exit
// when hdr==0. Reconstruct the exact A row in LDS, 8 parallel 32-lane
// candidate dots, exact top-2 with global-index tie-break.
__global__ __launch_bounds__(256) void refine2(const unsigned short* __restrict__ Phi,
                                               const char* __restrict__ Plo,
                                               const unsigned short* __restrict__ Khi,
                                               const char* __restrict__ Klo,
                                               const float* __restrict__ normP,
                                               const float* __restrict__ normK,
                                               const int* __restrict__ colidx,
                                               const int* __restrict__ n0p,
                                               const int* __restrict__ wl_hdr,
                                               const int* __restrict__ wl_cand,
                                               float* __restrict__ w01,
                                               int* __restrict__ i01) {
    __shared__ float sAf[C_DIM];     // 16 KB exact A row
    __shared__ float s_rcv[16];
    __shared__ int   s_rcj[16];

    const int item = blockIdx.x;
    const int cnt  = wl_hdr[item];
    if (cnt == 0) return;            // trusted or out-of-range -> nothing

    const int n0 = *n0p;
    const int r  = item >> 1;
    const int zz = item & 1;
    const int row = colidx[n0 + r];  // original masked row
    const int t   = threadIdx.x;
    const int grp = t >> 5, l32 = t & 31;
    const float nr = normP[row];

    // reconstruct exact A row
    {
        const unsigned short* Ah = Phi + (size_t)row * C_DIM;
        const char*           Al = Plo + (size_t)row * C_DIM;
        #pragma unroll
        for (int s = 0; s < 2; s++) {
            int c = t * 16 + s * 8;
            ushort8 hb = *(const ushort8*)&Ah[c];
            schar8  lb = *(const schar8*)&Al[c];
            #pragma unroll
            for (int e = 0; e < 8; e++) sAf[c + e] = h2f(hb[e]) + lo_dec(lb[e], hb[e]);
        }
    }
    __syncthreads();

    #pragma unroll
    for (int p = 0; p < 2; p++) {
        if (p == 1 && cnt <= 8) break;          // uniform
        const int q = grp + 8 * p;
        float acc = 0.0f;
        int gj = 0; float nb = 1.0f;
        if (q < cnt) {
            const int cs = wl_cand[item * 16 + q];
            gj = colidx[cs];
            nb = (cs < n0) ? normK[gj] : normP[gj];
            const unsigned short* bh_row = ((cs < n0) ? Khi : Phi) + (size_t)gj * C_DIM;
            const char*           bl_row = ((cs < n0) ? Klo : Plo) + (size_t)gj * C_DIM;
            #pragma unroll 4
            for (int it = 0; it < 16; it++) {
                int c = it * 256 + l32 * 8;
                ushort8 hb = *(const ushort8*)&bh_row[c];
                schar8  lb = *(const schar8*)&bl_row[c];
                #pragma unroll
                for (int e = 0; e < 8; e++)
                    acc = fmaf(sAf[c + e], h2f(hb[e]) + lo_dec(lb[e], hb[e]), acc);
            }
        }
        #pragma unroll
        for (int off = 16; off > 0; off >>= 1) acc += __shfl_xor(acc, off);
        if (l32 == 0 && q < cnt) {
            s_rcv[q] = acc * rsqrtf(nr * nb);
            s_rcj[q] = gj;
        }
    }
    __syncthreads();

    if (t == 0) {
        float v1 = -INFINITY, v2 = -INFINITY;
        int   j1 = 0x7FFFFFFF, j2 = 0x7FFFFFFF;
        for (int q = 0; q < cnt; q++) {
            float cvx = s_rcv[q];
            int   j   = s_rcj[q];
            if (cvx > v1 || (cvx == v1 && j < j1)) {
                v2 = v1; j2 = j1; v1 = cvx; j1 = j;
            } else if (cvx > v2 || (cvx == v2 && j < j2)) {
                v2 = cvx; j2 = j;
            }
        }
        if (j1 == 0x7FFFFFFF) j1 = 0;   // degenerate-partition guard
        if (j2 == 0x7FFFFFFF) j2 = j1;
        int base = (zz * N_TOT + row) * 2;
        w01[base]     = v1;
        w01[base + 1] = v2;
        i01[base]     = j1;
        i01[base + 1] = j2;
    }
}

// ---------------------------------------------------------------------------
// output: FOUR channels per block, means+softmax computed redundantly per
// block from w01/flag (L2-resident, removes the means_k launch). Stage 4
// G/Kn rows in LDS, copies from staged registers, gathers served from LDS.
// grid (1024), block 256.
__global__ __launch_bounds__(256) void output_kernel(const float* __restrict__ G,
                                                     const float* __restrict__ Kn,
                                                     const float* __restrict__ flag,
                                                     const float* __restrict__ w01,
                                                     const int* __restrict__ i01,
                                                     float* __restrict__ out) {
    __shared__ float sG[4][N_TOT];
    __shared__ float sKn[4][N_TOT];
    __shared__ float red[5][4];
    __shared__ float swts[4];
    const int c0 = blockIdx.x * 4;
    const int t  = threadIdx.x;
    const int n4 = t * 4;
    const int wave = t >> 6, lane = t & 63;

    // ---- means + softmax (redundant per block; reads hit L2) ----
    float4 fv = *(const float4*)&flag[n4];
    const float fa[4] = {fv.x, fv.y, fv.z, fv.w};
    float pm[5] = {};
    #pragma unroll
    for (int e = 0; e < 4; e++) {
        int n = n4 + e;
        if (fa[e] == 1.0f) {
            pm[0] += 1.0f;
            pm[1] += w01[n * 2 + 0];
            pm[2] += w01[n * 2 + 1];
            pm[3] += w01[2 * N_TOT + n * 2 + 0];
            pm[4] += w01[2 * N_TOT + n * 2 + 1];
        }
    }
    #pragma unroll
    for (int i = 0; i < 5; i++)
        #pragma unroll
        for (int off = 32; off > 0; off >>= 1)
            pm[i] += __shfl_xor(pm[i], off);
    if (lane == 0) {
        #pragma unroll
        for (int i = 0; i < 5; i++) red[i][wave] = pm[i];
    }

    // ---- stage 4 channels + passthrough copies ----
    #pragma unroll
    for (int ch = 0; ch < 4; ch++) {
        int c = c0 + ch;
        float4 gv = *(const float4*)&G[c * N_TOT + n4];
        float4 kv = *(const float4*)&Kn[c * N_TOT + n4];
        *(float4*)&sG[ch][n4]  = gv;
        *(float4*)&sKn[ch][n4] = kv;
        *(float4*)&out[c * N_TOT + n4] = gv;
        *(float4*)&out[C_DIM * N_TOT + c * N_TOT + n4] = kv;
    }
    __syncthreads();

    if (t == 0) {
        float tot[5];
        #pragma unroll
        for (int i = 0; i < 5; i++)
            tot[i] = red[i][0] + red[i][1] + red[i][2] + red[i][3];
        float inv = 1.0f / tot[0];
        float mv[4] = {tot[1] * inv, tot[2] * inv, tot[3] * inv, tot[4] * inv};
        float mx = fmaxf(fmaxf(mv[0], mv[1]), fmaxf(mv[2], mv[3]));
        float e[4], s = 0.0f;
        #pragma unroll
        for (int q = 0; q < 4; q++) { e[q] = expf(mv[q] - mx); s += e[q]; }
        #pragma unroll
        for (int q = 0; q < 4; q++) swts[q] = e[q] / s;
    }
    __syncthreads();
    const float w0 = swts[0], w1 = swts[1], w2 = swts[2], w3 = swts[3];

    float val[4][4];
    #pragma unroll
    for (int e = 0; e < 4; e++) {
        int n = n4 + e;
        float v[4] = {0.f, 0.f, 0.f, 0.f};
        if (fa[e] == 1.0f) {
            int2 i0 = *(const int2*)&i01[n * 2];
            int2 i1 = *(const int2*)&i01[2 * N_TOT + n * 2];
            #pragma unroll
            for (int ch = 0; ch < 4; ch++)
                v[ch] = w0 * sKn[ch][i0.x] + w1 * sKn[ch][i0.y]
                      + w2 * sG[ch][i1.x]  + w3 * sG[ch][i1.y];
        }
        if (n == 0) {
            bool m0 = (flag[0] == 1.0f);
            int2 i0 = m0 ? *(const int2*)&i01[0]         : make_int2(-1, -1);
            int2 i1 = m0 ? *(const int2*)&i01[2 * N_TOT] : make_int2(-1, -1);
            #pragma unroll
            for (int ch = 0; ch < 4; ch++) {
                if (!(m0 && i0.x == 0)) v[ch] += w0 * sKn[ch][0];
                if (!(m0 && i0.y == 0)) v[ch] += w1 * sKn[ch][0];
                if (!(m0 && i1.x == 0)) v[ch] += w2 * sG[ch][0];
                if (!(m0 && i1.y == 0)) v[ch] += w3 * sG[ch][0];
            }
        }
        #pragma unroll
        for (int ch = 0; ch < 4; ch++) val[ch][e] = v[ch];
    }
    #pragma unroll
    for (int ch = 0; ch < 4; ch++)
        *(float4*)&out[2 * C_DIM * N_TOT + (c0 + ch) * N_TOT + n4] =
            make_float4(val[ch][0], val[ch][1], val[ch][2], val[ch][3]);
}

// ---------------------------------------------------------------------------
extern "C" void kernel_launch(void* const* d_in, const int* in_sizes, int n_in,
                              void* d_out, int out_size, void* d_ws, size_t ws_size,
                              hipStream_t stream) {
    const float* G    = (const float*)d_in[0];
    const float* Kn   = (const float*)d_in[1];
    const float* flag = (const float*)d_in[2];
    float* out = (float*)d_out;

    // ws layout (~56.5 MB)
    char* p = (char*)d_ws;
    unsigned short* Phi = (unsigned short*)p;  p += (size_t)N_TOT * C_DIM * 2;  // 8 MB
    unsigned short* Khi = (unsigned short*)p;  p += (size_t)N_TOT * C_DIM * 2;  // 8 MB
    char* Plo = p;                             p += (size_t)N_TOT * C_DIM;      // 4 MB
    char* Klo = p;                             p += (size_t)N_TOT * C_DIM;      // 4 MB
    float* dotPart = (float*)p;                p += (size_t)8 * N_TOT * N_TOT * 4; // 32 MB
    float* normP   = (float*)p;                p += N_TOT * 4;
    float* normK   = (float*)p;                p += N_TOT * 4;
    float* w01     = (float*)p;                p += 4 * N_TOT * 4;
    int*   i01     = (int*)p;                  p += 4 * N_TOT * 4;
    int*   colidx  = (int*)p;                  p += N_TOT * 4;
    int*   n0p     = (int*)p;                  p += 16;
    int*   wl_hdr  = (int*)p;                  p += 2 * N_TOT * 4;
    int*   wl_cand = (int*)p;

    // zero only the atomically-accumulated norms (8 KB)
    hipMemsetAsync(normP, 0, 2 * N_TOT * sizeof(float), stream);

    split_norms<<<dim3(64, 16, 2), 256, 0, stream>>>(G, Kn, flag, Phi, Plo, Khi, Klo,
                                                     normP, normK, colidx, n0p);
    gemm_coarse<<<dim3(16, 8, 8), 256, 0, stream>>>(Phi, Khi, colidx, n0p, dotPart);
    select_k<<<1024, 256, 0, stream>>>(dotPart, normP, normK, colidx, n0p,
                                       w01, i01, wl_hdr, wl_cand);
    refine2<<<2048, 256, 0, stream>>>(Phi, Plo, Khi, Klo, normP, normK, colidx, n0p,
                                      wl_hdr, wl_cand, w01, i01);
    output_kernel<<<1024, 256, 0, stream>>>(G, Kn, flag, w01, i01, out);
}